// Round 11
// baseline (1749.561 us; speedup 1.0000x reference)
//
#include <hip/hip_runtime.h>
#include <hip/hip_bf16.h>
#include <cstdint>

// B=8, N=8192, S=1024, C=64
// branch0: r=0.4, K=32, layers 64x67, 64x64, 128x64
// branch1: r=0.8, K=64, layers 64x67, 128x64, 256x128

typedef __attribute__((ext_vector_type(8))) short short8;
typedef __attribute__((ext_vector_type(4))) float f32x4;
typedef __attribute__((ext_vector_type(2))) float f32x2;

__device__ __forceinline__ float bf2f(unsigned short u) {
    return __uint_as_float(((unsigned)u) << 16);
}
__device__ __forceinline__ unsigned short f2bf(float f) {
    unsigned u = __float_as_uint(f);
    return (unsigned short)((u + 0x7fffu + ((u >> 16) & 1u)) >> 16);  // RNE
}

// Wave-64 reductions on the VALU pipe via DPP (rocPRIM pattern): result in lane 63.
__device__ __forceinline__ float wave_red_max_f32(float v) {
#define DPPSTEP(ctrl)                                                                  \
    {                                                                                  \
        int _t = __builtin_amdgcn_update_dpp((int)0xFF800000, __float_as_int(v), ctrl, \
                                             0xf, 0xf, false);                         \
        v = fmaxf(v, __int_as_float(_t));                                              \
    }
    DPPSTEP(0x111) DPPSTEP(0x112) DPPSTEP(0x114) DPPSTEP(0x118) DPPSTEP(0x142) DPPSTEP(0x143)
#undef DPPSTEP
    return v;
}
__device__ __forceinline__ unsigned wave_red_min_u32(unsigned v) {
#define DPPSTEP(ctrl)                                                                   \
    {                                                                                   \
        unsigned _t = (unsigned)__builtin_amdgcn_update_dpp((int)0xFFFFFFFF, (int)v,    \
                                                            ctrl, 0xf, 0xf, false);     \
        v = v < _t ? v : _t;                                                            \
    }
    DPPSTEP(0x111) DPPSTEP(0x112) DPPSTEP(0x114) DPPSTEP(0x118) DPPSTEP(0x142) DPPSTEP(0x143)
#undef DPPSTEP
    return v;
}
__device__ __forceinline__ unsigned long long u64max(unsigned long long a, unsigned long long b) {
    return a > b ? a : b;
}
__device__ __forceinline__ unsigned u32min(unsigned a, unsigned b) { return a < b ? a : b; }

// Packed-f32 dist update for 4 point-pairs: one asm block, stage-interleaved
// (4-way ILP), per-pair temps consumed immediately after (no live-range growth —
// R7's spill failure came from per-op asm statements with persistent dests).
// a+(-b) == a-b bit-exactly in IEEE; rounding order (dx²+dy²)+dz² preserved ->
// trajectory bit-identical to the scalar version.
#define PK4(K0)                                                               \
    {                                                                         \
        f32x2 a0, a1, a2, a3, b0, b1, b2, b3, e0, e1, e2, e3;                 \
        asm("v_pk_add_f32 %[a0], %[x0], %[n0]\n\t"                            \
            "v_pk_add_f32 %[a1], %[x1], %[n0]\n\t"                            \
            "v_pk_add_f32 %[a2], %[x2], %[n0]\n\t"                            \
            "v_pk_add_f32 %[a3], %[x3], %[n0]\n\t"                            \
            "v_pk_add_f32 %[b0], %[y0], %[n1]\n\t"                            \
            "v_pk_add_f32 %[b1], %[y1], %[n1]\n\t"                            \
            "v_pk_add_f32 %[b2], %[y2], %[n1]\n\t"                            \
            "v_pk_add_f32 %[b3], %[y3], %[n1]\n\t"                            \
            "v_pk_add_f32 %[e0], %[z0], %[n2]\n\t"                            \
            "v_pk_add_f32 %[e1], %[z1], %[n2]\n\t"                            \
            "v_pk_add_f32 %[e2], %[z2], %[n2]\n\t"                            \
            "v_pk_add_f32 %[e3], %[z3], %[n2]\n\t"                            \
            "v_pk_mul_f32 %[a0], %[a0], %[a0]\n\t"                            \
            "v_pk_mul_f32 %[a1], %[a1], %[a1]\n\t"                            \
            "v_pk_mul_f32 %[a2], %[a2], %[a2]\n\t"                            \
            "v_pk_mul_f32 %[a3], %[a3], %[a3]\n\t"                            \
            "v_pk_mul_f32 %[b0], %[b0], %[b0]\n\t"                            \
            "v_pk_mul_f32 %[b1], %[b1], %[b1]\n\t"                            \
            "v_pk_mul_f32 %[b2], %[b2], %[b2]\n\t"                            \
            "v_pk_mul_f32 %[b3], %[b3], %[b3]\n\t"                            \
            "v_pk_mul_f32 %[e0], %[e0], %[e0]\n\t"                            \
            "v_pk_mul_f32 %[e1], %[e1], %[e1]\n\t"                            \
            "v_pk_mul_f32 %[e2], %[e2], %[e2]\n\t"                            \
            "v_pk_mul_f32 %[e3], %[e3], %[e3]\n\t"                            \
            "v_pk_add_f32 %[a0], %[a0], %[b0]\n\t"                            \
            "v_pk_add_f32 %[a1], %[a1], %[b1]\n\t"                            \
            "v_pk_add_f32 %[a2], %[a2], %[b2]\n\t"                            \
            "v_pk_add_f32 %[a3], %[a3], %[b3]\n\t"                            \
            "v_pk_add_f32 %[a0], %[a0], %[e0]\n\t"                            \
            "v_pk_add_f32 %[a1], %[a1], %[e1]\n\t"                            \
            "v_pk_add_f32 %[a2], %[a2], %[e2]\n\t"                            \
            "v_pk_add_f32 %[a3], %[a3], %[e3]"                                \
            : [a0] "=&v"(a0), [a1] "=&v"(a1), [a2] "=&v"(a2), [a3] "=&v"(a3), \
              [b0] "=&v"(b0), [b1] "=&v"(b1), [b2] "=&v"(b2), [b3] "=&v"(b3), \
              [e0] "=&v"(e0), [e1] "=&v"(e1), [e2] "=&v"(e2), [e3] "=&v"(e3)  \
            : [x0] "v"(px[(K0)]), [x1] "v"(px[(K0) + 1]),                     \
              [x2] "v"(px[(K0) + 2]), [x3] "v"(px[(K0) + 3]),                 \
              [y0] "v"(py[(K0)]), [y1] "v"(py[(K0) + 1]),                     \
              [y2] "v"(py[(K0) + 2]), [y3] "v"(py[(K0) + 3]),                 \
              [z0] "v"(pz[(K0)]), [z1] "v"(pz[(K0) + 1]),                     \
              [z2] "v"(pz[(K0) + 2]), [z3] "v"(pz[(K0) + 3]),                 \
              [n0] "v"(nc0), [n1] "v"(nc1), [n2] "v"(nc2));                   \
        float q0x = fminf(d[(K0)].x, a0.x), q0y = fminf(d[(K0)].y, a0.y);     \
        float q1x = fminf(d[(K0) + 1].x, a1.x);                               \
        float q1y = fminf(d[(K0) + 1].y, a1.y);                               \
        float q2x = fminf(d[(K0) + 2].x, a2.x);                               \
        float q2y = fminf(d[(K0) + 2].y, a2.y);                               \
        float q3x = fminf(d[(K0) + 3].x, a3.x);                               \
        float q3y = fminf(d[(K0) + 3].y, a3.y);                               \
        d[(K0)].x = q0x; d[(K0)].y = q0y;                                     \
        d[(K0) + 1].x = q1x; d[(K0) + 1].y = q1y;                             \
        d[(K0) + 2].x = q2x; d[(K0) + 2].y = q2y;                             \
        d[(K0) + 3].x = q3x; d[(K0) + 3].y = q3y;                             \
        vmax = fmaxf(vmax, fmaxf(fmaxf(q0x, q0y), fmaxf(q1x, q1y)));         \
        vmax = fmaxf(vmax, fmaxf(fmaxf(q2x, q2y), fmaxf(q3x, q3y)));         \
    }

// ---------------- workspace layout (bytes); peak = 224,395,264 ------------------
static const size_t OFF_WBF   = 0;          // packed bf16 weights, 65536 elems (128 KB)
static const size_t OFF_STATS = 262144;     // 704 ch * 128 slots * 2 * 4B
static const size_t STATS_BYTES = 720896;
static const size_t OFF_AFF   = 1048576;    // per-layer scale/shift
static const size_t OFF_IDX0  = 2097152;    // 8*1024*32 ints
static const size_t OFF_IDX1  = 3145728;    // 8*1024*64 ints
static const size_t OFF_MX    = 5242880;    // 256*8192 fp32
static const size_t OFF_MN    = 13631488;
static const size_t OFF_Y0    = 22020096;   // bf16 X^T [NCOL][64]  (max 67 MB)
static const size_t OFF_Y1    = 90177536;   // bf16 X^T [NCOL][128] (max 134 MB)
static const size_t OFF_FEATT = 211812352;  // bf16 [8*8192][96] = 12.58 MB, overlaps Y1 tail
// (featTp last read in br1-L0; Y1 beyond 121.6 MB only written by br1-L1, which runs later)

// ---------------- fused pre-kernel (256 threads/block):
// FPS (blocks 0..7) + feat transpose (8..1031) + weight pack (1032..1287) ----
__global__ __launch_bounds__(256) void fused_pre(
    const float* __restrict__ xyz, const float* __restrict__ feat,
    float* __restrict__ newxyz, unsigned short* __restrict__ ft,
    const float* __restrict__ w0, const float* __restrict__ w1, const float* __restrict__ w2,
    const float* __restrict__ w3, const float* __restrict__ w4, const float* __restrict__ w5,
    unsigned short* __restrict__ wb) {
    __shared__ union alignas(16) SM {
        struct {
            float ptsx[8200], ptsy[8200], ptsz[8200];
            float ldsM[16][3];
            float meanv[3];
            unsigned long long sKey[2][4];
            float cbuf[3072];  // selected centroids; written to global once at the end
        } f;
        float tile[64][65];
    } sm;
    const int tid = threadIdx.x;

    if (blockIdx.x >= 1032) {
        // ---- weight pack: w[M][K] f32 -> wb[Mp][Kp] bf16 (zero pad) ----
        int id = (int)(blockIdx.x - 1032) * 256 + tid;  // 0..65535
        const int psz[6] = {6144, 4096, 8192, 6144, 8192, 32768};
        const int Kp[6] = {96, 64, 64, 96, 64, 128};
        const int Ks[6] = {67, 64, 64, 67, 64, 128};
        const float* wp[6] = {w0, w1, w2, w3, w4, w5};
        int off = 0;
        for (int l = 0; l < 6; ++l) {
            if (id < off + psz[l]) {
                int e = id - off;
                int m = e / Kp[l], k = e - m * Kp[l];
                float v = (k < Ks[l]) ? wp[l][m * Ks[l] + k] : 0.f;
                wb[id] = f2bf(v);
                return;
            }
            off += psz[l];
        }
        return;
    }

    if (blockIdx.x >= 8) {
        // ---- featTp: [8][8192][96] bf16; c0..2 = xyz, c3..66 = feat, rest 0 ----
        int tb = (int)blockIdx.x - 8;  // 0..1023
        int b = tb >> 7;
        int j0 = (tb & 127) * 64;
#pragma unroll
        for (int i = 0; i < 16; ++i) {
            int e = i * 256 + tid;
            int c = e >> 6, j = e & 63;
            sm.tile[j][c] = feat[((size_t)b * 64 + c) * 8192 + j0 + j];
        }
        __syncthreads();
#pragma unroll
        for (int i = 0; i < 16; ++i) {
            int e = i * 256 + tid;
            int j = e >> 6, c = e & 63;
            ft[((size_t)(b * 8192 + j0 + j)) * 96 + 3 + c] = f2bf(sm.tile[j][c]);
        }
        if (tid < 64) {
            int j = tid;
            size_t base = ((size_t)(b * 8192 + j0 + j)) * 96;
            const float* xp = xyz + ((size_t)b * 8192 + j0 + j) * 3;
            ft[base + 0] = f2bf(xp[0]);
            ft[base + 1] = f2bf(xp[1]);
            ft[base + 2] = f2bf(xp[2]);
        } else if (tid < 128) {
            int j = tid - 64;
            size_t base = ((size_t)(b * 8192 + j0 + j)) * 96;
            for (int c = 67; c < 96; ++c) ft[base + c] = 0;
        }
        return;
    }

    // ---- FPS: 4 waves (1/SIMD), 32 pts/thread as 16 float2 pairs (R9-proven) ----
    const int b = blockIdx.x;
    const int t = tid;
    const int lane = t & 63, wv = t >> 6;  // wv 0..3
    const float* xb = xyz + (size_t)b * 8192 * 3;

    f32x2 px[16], py[16], pz[16], d[16];
#pragma unroll
    for (int k = 0; k < 16; ++k) {
        int q0 = t + 256 * (2 * k);
        int q1 = t + 256 * (2 * k + 1);
        px[k].x = xb[q0 * 3 + 0]; px[k].y = xb[q1 * 3 + 0];
        py[k].x = xb[q0 * 3 + 1]; py[k].y = xb[q1 * 3 + 1];
        pz[k].x = xb[q0 * 3 + 2]; pz[k].y = xb[q1 * 3 + 2];
        d[k].x = 1e10f; d[k].y = 1e10f;
        sm.f.ptsx[q0 + 1] = px[k].x; sm.f.ptsx[q1 + 1] = px[k].y;
        sm.f.ptsy[q0 + 1] = py[k].x; sm.f.ptsy[q1 + 1] = py[k].y;
        sm.f.ptsz[q0 + 1] = pz[k].x; sm.f.ptsz[q1 + 1] = pz[k].y;
    }
    // ---- mean: bit-identical replication of the v1 1024-partial tree ----
    {
        float sx[4], sy[4], sz[4];
#pragma unroll
        for (int m = 0; m < 4; ++m) {
            int u = (t + 256 * m + 1023) & 1023;
            float ax = 0.f, ay = 0.f, az = 0.f;
#pragma unroll
            for (int jj = 0; jj < 8; ++jj) {
                int ia = u + 1024 * jj;
                ax += xb[ia * 3 + 0]; ay += xb[ia * 3 + 1]; az += xb[ia * 3 + 2];
            }
            sx[m] = ax; sy[m] = ay; sz[m] = az;
        }
#pragma unroll
        for (int off = 32; off; off >>= 1) {
#pragma unroll
            for (int m = 0; m < 4; ++m) {
                sx[m] += __shfl_xor(sx[m], off, 64);
                sy[m] += __shfl_xor(sy[m], off, 64);
                sz[m] += __shfl_xor(sz[m], off, 64);
            }
        }
        if (lane == 0) {
#pragma unroll
            for (int m = 0; m < 4; ++m) {
                sm.f.ldsM[wv + 4 * m][0] = sx[m];
                sm.f.ldsM[wv + 4 * m][1] = sy[m];
                sm.f.ldsM[wv + 4 * m][2] = sz[m];
            }
        }
    }
    __syncthreads();
    if (t < 3) {
        float s = 0.f;
        for (int w = 0; w < 16; ++w) s += sm.f.ldsM[w][t];
        sm.f.meanv[t] = s * (1.f / 8192.f);
    }
    __syncthreads();
    float cx = sm.f.meanv[0], cy = sm.f.meanv[1], cz = sm.f.meanv[2];
    const float mmx = cx, mmy = cy, mmz = cz;  // mean point (pts idx 0), owned by t0
    float dm = 1e10f;
    if (t == 0) { sm.f.ptsx[0] = cx; sm.f.ptsy[0] = cy; sm.f.ptsz[0] = cz; }
    __syncthreads();

    for (int it = 0; it < 1024; ++it) {
        if (t == 0) {
            sm.f.cbuf[it * 3 + 0] = cx;
            sm.f.cbuf[it * 3 + 1] = cy;
            sm.f.cbuf[it * 3 + 2] = cz;
        }
        f32x2 nc0, nc1, nc2;
        nc0.x = -cx; nc0.y = -cx;
        nc1.x = -cy; nc1.y = -cy;
        nc2.x = -cz; nc2.y = -cz;
        float vmax = -1e30f;
        PK4(0) PK4(4) PK4(8) PK4(12)
        if (t == 0) {
            float dx = __fsub_rn(mmx, cx);
            float dy = __fsub_rn(mmy, cy);
            float dz = __fsub_rn(mmz, cz);
            float dd = __fadd_rn(__fadd_rn(__fmul_rn(dx, dx), __fmul_rn(dy, dy)), __fmul_rn(dz, dz));
            dm = fminf(dm, dd);
            vmax = fmaxf(vmax, dm);
        }
        float wm = wave_red_max_f32(vmax);
        float bmaxw = __int_as_float(__builtin_amdgcn_readlane(__float_as_int(wm), 63));
        unsigned m2[16];
#pragma unroll
        for (int k = 0; k < 16; ++k) {
            unsigned i0 = (d[k].x == bmaxw) ? (unsigned)(t + 256 * (2 * k) + 1) : 0xFFFFFFFFu;
            unsigned i1 = (d[k].y == bmaxw) ? (unsigned)(t + 256 * (2 * k + 1) + 1) : 0xFFFFFFFFu;
            m2[k] = u32min(i0, i1);
        }
#pragma unroll
        for (int s = 8; s; s >>= 1)
#pragma unroll
            for (int k = 0; k < s; ++k) m2[k] = u32min(m2[k], m2[k + s]);
        unsigned mi = m2[0];
        if (t == 0 && dm == bmaxw) mi = 0u;
        unsigned wmin = wave_red_min_u32(mi);
        unsigned miw = (unsigned)__builtin_amdgcn_readlane((int)wmin, 63);
        int par = it & 1;
        if (lane == 0)
            sm.f.sKey[par][wv] = ((unsigned long long)__float_as_uint(bmaxw) << 32) |
                                 (unsigned long long)(8192u - miw);
        __syncthreads();  // the ONLY barrier per iteration (parity-double-buffered slots)
        unsigned long long ka[4];
#pragma unroll
        for (int i = 0; i < 4; ++i) ka[i] = sm.f.sKey[par][i];  // same-address broadcasts
        unsigned long long kk = u64max(u64max(ka[0], ka[1]), u64max(ka[2], ka[3]));
        int far = 8192 - (int)(unsigned)(kk & 0xffffffffull);
        cx = sm.f.ptsx[far];  // uniform LDS broadcast
        cy = sm.f.ptsy[far];
        cz = sm.f.ptsz[far];
    }
    __syncthreads();
    float* ob = newxyz + (size_t)b * 3072;
#pragma unroll
    for (int i = 0; i < 12; ++i) ob[t + 256 * i] = sm.f.cbuf[t + 256 * i];
}

// ---------------- merged ball query: blocks 0..2047 br0 (K=32), 2048..4095 br1 --
__global__ void ball_query2(const float* __restrict__ xyz, const float* __restrict__ newxyz,
                            int* __restrict__ idx0, int* __restrict__ idx1) {
    int bid = blockIdx.x;
    int br = (bid >= 2048);
    int K = br ? 64 : 32;
    float r2 = br ? (0.8f * 0.8f) : (0.4f * 0.4f);
    int* idxout = br ? idx1 : idx0;
    int wid = (((bid & 2047) * 256) + threadIdx.x) >> 6;  // query id, 0..8191
    int lane = threadIdx.x & 63;
    int b = wid >> 10;
    const float* q = newxyz + (size_t)wid * 3;
    float qx = q[0], qy = q[1], qz = q[2];
    const float* xb = xyz + (size_t)b * 8192 * 3;
    int* out = idxout + (size_t)wid * K;
    int count = 0;
    int first = 0;
    for (int base = 0; base < 8192 && count < K; base += 64) {
        int j = base + lane;
        float dx = __fsub_rn(xb[j * 3 + 0], qx);
        float dy = __fsub_rn(xb[j * 3 + 1], qy);
        float dz = __fsub_rn(xb[j * 3 + 2], qz);
        float d2 = __fadd_rn(__fadd_rn(__fmul_rn(dx, dx), __fmul_rn(dy, dy)), __fmul_rn(dz, dz));
        bool in = d2 < r2;
        unsigned long long m = __ballot(in);
        if (count == 0 && m) first = base + __ffsll((long long)m) - 1;
        if (in) {
            int pos = count + __popcll(m & ((1ull << lane) - 1ull));
            if (pos < K) out[pos] = j;
        }
        count += __popcll(m);
    }
    if (count < K) {
        int fillv = (count > 0) ? first : 0;
        for (int p = count + lane; p < K; p += 64) out[p] = fillv;
    }
}

// ---------------- MFMA GEMM, NT n-tiles (NT*16 cols) per block ------------------
// Fragment-major conflict-free LDS staging (R8-proven).
template <int Mp, int Kp, int IN_MODE, int OUT_MODE, int KSH, int NT>
__global__ __launch_bounds__(256) void gemm_mfma(
    const unsigned short* __restrict__ Wb, const unsigned short* __restrict__ Xin,
    const float* __restrict__ aff, const int* __restrict__ idx,
    const unsigned short* __restrict__ ftp, const float* __restrict__ newxyz,
    unsigned short* __restrict__ Yout, float* __restrict__ MX, float* __restrict__ MN,
    float* __restrict__ statS, float* __restrict__ statQ) {
    constexpr int MT = Mp / 64;
    constexpr int KS = Kp / 32;
    constexpr int NC = NT * 16;              // cols per block
    constexpr int NCHUNK = NT * KS * 64;     // 16B chunks in Bs
    __shared__ unsigned short Bs[NCHUNK * 8];
    __shared__ float sAux[NT * 64];          // IN0: idx + 3q per col; IN1: 2*Kp affine
    int* sAuxI = (int*)sAux;

    const int tid = threadIdx.x;
    const int w = tid >> 6;
    const int lane = tid & 63;
    const int n = lane & 15;
    const int quad = lane >> 4;
    const int rbase = w * (Mp / 4);
    const long col0 = (long)blockIdx.x * NC;

    short8 a[MT][KS];
#pragma unroll
    for (int mt = 0; mt < MT; ++mt)
#pragma unroll
        for (int ks = 0; ks < KS; ++ks)
            a[mt][ks] = *(const short8*)(Wb + (size_t)(rbase + mt * 16 + n) * Kp + ks * 32 + quad * 8);

    if constexpr (IN_MODE == 0) {
        for (int c = tid; c < NC; c += 256) {
            long colg = col0 + c;
            sAuxI[c] = idx[colg];
            long sk = colg >> KSH;
            sAux[NC + c] = newxyz[sk * 3 + 0];
            sAux[2 * NC + c] = newxyz[sk * 3 + 1];
            sAux[3 * NC + c] = newxyz[sk * 3 + 2];
        }
    } else {
        if (tid < 2 * Kp) sAux[tid] = aff[tid];
    }
    __syncthreads();

    // ---- Phase 1: build B-tile in LDS, chunk p = i*256+tid (lane-sequential) ----
#pragma unroll
    for (int i = 0; i < NCHUNK / 256; ++i) {
        int p = i * 256 + tid;
        int pl = p & 63;
        int pn = pl & 15;
        int pq = pl >> 4;
        int rest = p >> 6;  // pnt*KS + pks
        int pks = rest % KS;
        int pnt = rest / KS;
        int col = pnt * 16 + pn;
        int kc = pks * 4 + pq;  // 16B chunk index along K
        short8 v;
        if constexpr (IN_MODE == 0) {
            const int bb = (int)(col0 >> (KSH + 10));
            int j = sAuxI[col];
            v = *(const short8*)(ftp + ((long)(bb * 8192 + j)) * 96 + kc * 8);
            if (kc == 0) {  // rel-xyz patch: channels 0..2
                v[0] = (short)f2bf(bf2f((unsigned short)v[0]) - sAux[NC + col]);
                v[1] = (short)f2bf(bf2f((unsigned short)v[1]) - sAux[2 * NC + col]);
                v[2] = (short)f2bf(bf2f((unsigned short)v[2]) - sAux[3 * NC + col]);
            }
        } else {
            short8 raw = *(const short8*)(Xin + (col0 + col) * (long)Kp + kc * 8);
#pragma unroll
            for (int e = 0; e < 8; ++e) {
                float xf = bf2f((unsigned short)raw[e]);
                xf = fmaxf(fmaf(xf, sAux[kc * 8 + e], sAux[Kp + kc * 8 + e]), 0.f);
                v[e] = (short)f2bf(xf);
            }
        }
        *(short8*)(&Bs[p * 8]) = v;
    }
    __syncthreads();

    // ---- Phase 2: MFMA from LDS fragments (lane-sequential ds_read_b128) ----
    f32x4 acc[MT][NT];
#pragma unroll
    for (int mt = 0; mt < MT; ++mt)
#pragma unroll
        for (int nt = 0; nt < NT; ++nt)
#pragma unroll
            for (int r = 0; r < 4; ++r) acc[mt][nt][r] = 0.f;

#pragma unroll
    for (int ks = 0; ks < KS; ++ks) {
#pragma unroll
        for (int nt = 0; nt < NT; ++nt) {
            short8 bfr = *(const short8*)(&Bs[((nt * KS + ks) * 64 + lane) * 8]);
#pragma unroll
            for (int mt = 0; mt < MT; ++mt)
                acc[mt][nt] = __builtin_amdgcn_mfma_f32_16x16x32_bf16(a[mt][ks], bfr, acc[mt][nt], 0, 0, 0);
        }
    }

    // ---- stats: per-channel sum / sumsq ----
    const int slot = (int)(blockIdx.x & 127);
#pragma unroll
    for (int mt = 0; mt < MT; ++mt)
#pragma unroll
        for (int r = 0; r < 4; ++r) {
            float s = 0.f, q = 0.f;
#pragma unroll
            for (int nt = 0; nt < NT; ++nt) {
                float v = acc[mt][nt][r];
                s += v;
                q = fmaf(v, v, q);
            }
#pragma unroll
            for (int off = 1; off < 16; off <<= 1) {
                s += __shfl_xor(s, off, 16);
                q += __shfl_xor(q, off, 16);
            }
            if (n == 0) {
                int ch = rbase + mt * 16 + quad * 4 + r;
                atomicAdd(statS + (size_t)ch * 128 + slot, s);
                atomicAdd(statQ + (size_t)ch * 128 + slot, q);
            }
        }

    if constexpr (OUT_MODE == 0) {
#pragma unroll
        for (int mt = 0; mt < MT; ++mt)
#pragma unroll
            for (int nt = 0; nt < NT; ++nt) {
                long col = col0 + nt * 16 + n;
                unsigned p0 = f2bf(acc[mt][nt][0]) | ((unsigned)f2bf(acc[mt][nt][1]) << 16);
                unsigned p1 = f2bf(acc[mt][nt][2]) | ((unsigned)f2bf(acc[mt][nt][3]) << 16);
                uint2 st; st.x = p0; st.y = p1;
                *(uint2*)(Yout + col * Mp + rbase + mt * 16 + quad * 4) = st;
            }
    } else {
        constexpr int GRP = (1 << KSH) / 16;  // n-tiles per K-sample group (2 or 4)
        constexpr int NG = NT / GRP;          // groups per block
#pragma unroll
        for (int mt = 0; mt < MT; ++mt)
#pragma unroll
            for (int r = 0; r < 4; ++r) {
#pragma unroll
                for (int gh = 0; gh < NG; ++gh) {
                    float mx = acc[mt][GRP * gh][r], mn = acc[mt][GRP * gh][r];
#pragma unroll
                    for (int e = 1; e < GRP; ++e) {
                        mx = fmaxf(mx, acc[mt][GRP * gh + e][r]);
                        mn = fminf(mn, acc[mt][GRP * gh + e][r]);
                    }
#pragma unroll
                    for (int off = 1; off < 16; off <<= 1) {
                        mx = fmaxf(mx, __shfl_xor(mx, off, 16));
                        mn = fminf(mn, __shfl_xor(mn, off, 16));
                    }
                    if (n == 0) {
                        int ch = rbase + mt * 16 + quad * 4 + r;
                        long g = (col0 >> KSH) + gh;
                        MX[(long)ch * 8192 + g] = mx;
                        MN[(long)ch * 8192 + g] = mn;
                    }
                }
            }
    }
}

// ---------------- finalize BN constants ----------------------------------------
__global__ void finalize_kernel(const float* __restrict__ sS, const float* __restrict__ sQ,
                                const float* __restrict__ g, const float* __restrict__ b,
                                float* __restrict__ aff, int C, float invCount) {
    int c = threadIdx.x + blockIdx.x * blockDim.x;
    if (c >= C) return;
    float s = 0.f, q = 0.f;
    for (int k = 0; k < 128; ++k) { s += sS[c * 128 + k]; q += sQ[c * 128 + k]; }
    float mean = s * invCount;
    float var = fmaxf(q * invCount - mean * mean, 0.f);
    float sc = g[c] / sqrtf(var + 1e-5f);
    float sh = b[c] - mean * sc;
    aff[c] = sc;
    aff[C + c] = sh;
}

// ---------------- final output -------------------------------------------------
__global__ void final_out_kernel(const float* __restrict__ MX, const float* __restrict__ MN,
                                 const float* __restrict__ aff, float* __restrict__ out1,
                                 int Cout, int cOff) {
    long i = (long)blockIdx.x * 256 + threadIdx.x;
    int c = (int)(i >> 13);
    int gidx = (int)(i & 8191);
    int b = gidx >> 10, s = gidx & 1023;
    float sc = aff[c], sh = aff[Cout + c];
    float v = fmaxf(fmaxf(sc * MX[i] + sh, sc * MN[i] + sh), 0.f);
    out1[((long)b * 384 + cOff + c) * 1024 + s] = v;
}

// ---------------- host ---------------------------------------------------------
extern "C" void kernel_launch(void* const* d_in, const int* in_sizes, int n_in,
                              void* d_out, int out_size, void* d_ws, size_t ws_size,
                              hipStream_t stream) {
    const float* xyz = (const float*)d_in[0];
    const float* feat = (const float*)d_in[1];
    const float *W[6], *G[6], *Bi[6];
    for (int l = 0; l < 6; ++l) {
        W[l] = (const float*)d_in[2 + l * 3];
        G[l] = (const float*)d_in[3 + l * 3];
        Bi[l] = (const float*)d_in[4 + l * 3];
    }
    char* ws = (char*)d_ws;
    float* out0 = (float*)d_out;
    float* out1 = (float*)d_out + 24576;

    unsigned short* wb = (unsigned short*)(ws + OFF_WBF);
    float* stats = (float*)(ws + OFF_STATS);
    float* affine = (float*)(ws + OFF_AFF);
    int* idx0 = (int*)(ws + OFF_IDX0);
    int* idx1 = (int*)(ws + OFF_IDX1);
    float* mx = (float*)(ws + OFF_MX);
    float* mn = (float*)(ws + OFF_MN);
    unsigned short* y0 = (unsigned short*)(ws + OFF_Y0);
    unsigned short* y1 = (unsigned short*)(ws + OFF_Y1);
    unsigned short* ftp = (unsigned short*)(ws + OFF_FEATT);

    hipMemsetAsync(stats, 0, STATS_BYTES, stream);
    fused_pre<<<1288, 256, 0, stream>>>(xyz, feat, out0, ftp, W[0], W[1], W[2], W[3], W[4],
                                        W[5], wb);
    ball_query2<<<4096, 256, 0, stream>>>(xyz, out0, idx0, idx1);

    const int wOff[6] = {0, 6144, 10240, 18432, 24576, 32768};
    int stOff[6], afOff[6];
    {
        const int Cs[6] = {64, 64, 128, 64, 128, 256};
        int so = 0, ao = 0;
        for (int l = 0; l < 6; ++l) {
            stOff[l] = so; so += Cs[l] * 256;
            afOff[l] = ao; ao += Cs[l] * 2;
        }
    }

    for (int br = 0; br < 2; ++br) {
        const int K = br ? 64 : 32;
        const long NCOL = 8L * 1024 * K;
        int* idx = br ? idx1 : idx0;
        const int l0 = br * 3, l1 = br * 3 + 1, l2 = br * 3 + 2;
        const int M2 = br ? 256 : 128;
        const float invCount = 1.f / (float)NCOL;
        const int nblk256 = (int)(NCOL / 256);
        const int nblk128 = (int)(NCOL / 128);
        const int nblk64 = (int)(NCOL / 64);

        if (br == 0) {
            gemm_mfma<64, 96, 0, 0, 5, 16><<<nblk256, 256, 0, stream>>>(
                wb + wOff[l0], nullptr, nullptr, idx, ftp, out0, y0, nullptr, nullptr,
                stats + stOff[l0], stats + stOff[l0] + 64 * 128);
            finalize_kernel<<<1, 256, 0, stream>>>(stats + stOff[l0], stats + stOff[l0] + 64 * 128,
                                                   G[l0], Bi[l0], affine + afOff[l0], 64, invCount);
            gemm_mfma<64, 64, 1, 0, 5, 16><<<nblk256, 256, 0, stream>>>(
                wb + wOff[l1], y0, affine + afOff[l0], nullptr, nullptr, nullptr, y1, nullptr,
                nullptr, stats + stOff[l1], stats + stOff[l1] + 64 * 128);
            finalize_kernel<<<1, 256, 0, stream>>>(stats + stOff[l1], stats + stOff[l1] + 64 * 128,
                                                   G[l1], Bi[l1], affine + afOff[l1], 64, invCount);
            gemm_mfma<128, 64, 1, 1, 5, 8><<<nblk128, 256, 0, stream>>>(
                wb + wOff[l2], y1, affine + afOff[l1], nullptr, nullptr, nullptr, nullptr, mx, mn,
                stats + stOff[l2], stats + stOff[l2] + 128 * 128);
            finalize_kernel<<<1, 256, 0, stream>>>(stats + stOff[l2], stats + stOff[l2] + 128 * 128,
                                                   G[l2], Bi[l2], affine + afOff[l2], 128, invCount);
        } else {
            gemm_mfma<64, 96, 0, 0, 6, 16><<<nblk256, 256, 0, stream>>>(
                wb + wOff[l0], nullptr, nullptr, idx, ftp, out0, y0, nullptr, nullptr,
                stats + stOff[l0], stats + stOff[l0] + 64 * 128);
            finalize_kernel<<<1, 256, 0, stream>>>(stats + stOff[l0], stats + stOff[l0] + 64 * 128,
                                                   G[l0], Bi[l0], affine + afOff[l0], 64, invCount);
            gemm_mfma<128, 64, 1, 0, 6, 8><<<nblk128, 256, 0, stream>>>(
                wb + wOff[l1], y0, affine + afOff[l0], nullptr, nullptr, nullptr, y1, nullptr,
                nullptr, stats + stOff[l1], stats + stOff[l1] + 128 * 128);
            finalize_kernel<<<1, 256, 0, stream>>>(stats + stOff[l1], stats + stOff[l1] + 128 * 128,
                                                   G[l1], Bi[l1], affine + afOff[l1], 128, invCount);
            gemm_mfma<256, 128, 1, 1, 6, 4><<<nblk64, 256, 0, stream>>>(
                wb + wOff[l2], y1, affine + afOff[l1], nullptr, nullptr, nullptr, nullptr, mx, mn,
                stats + stOff[l2], stats + stOff[l2] + 256 * 128);
            finalize_kernel<<<1, 256, 0, stream>>>(stats + stOff[l2], stats + stOff[l2] + 256 * 128,
                                                   G[l2], Bi[l2], affine + afOff[l2], 256, invCount);
        }

        final_out_kernel<<<(M2 * 8192) / 256, 256, 0, stream>>>(mx, mn, affine + afOff[l2], out1,
                                                                M2, br ? 128 : 0);
    }
}

// Round 12
// 1636.096 us; speedup vs baseline: 1.0694x; 1.0694x over previous
//
#include <hip/hip_runtime.h>
#include <hip/hip_bf16.h>
#include <cstdint>

// B=8, N=8192, S=1024, C=64
// branch0: r=0.4, K=32, layers 64x67, 64x64, 128x64
// branch1: r=0.8, K=64, layers 64x67, 128x64, 256x128

typedef __attribute__((ext_vector_type(8))) short short8;
typedef __attribute__((ext_vector_type(4))) float f32x4;
typedef __attribute__((ext_vector_type(2))) float f32x2;

__device__ __forceinline__ float bf2f(unsigned short u) {
    return __uint_as_float(((unsigned)u) << 16);
}
__device__ __forceinline__ unsigned short f2bf(float f) {
    unsigned u = __float_as_uint(f);
    return (unsigned short)((u + 0x7fffu + ((u >> 16) & 1u)) >> 16);  // RNE
}

// Wave-64 reductions on the VALU pipe via DPP (rocPRIM pattern): result in lane 63.
__device__ __forceinline__ float wave_red_max_f32(float v) {
#define DPPSTEP(ctrl)                                                                  \
    {                                                                                  \
        int _t = __builtin_amdgcn_update_dpp((int)0xFF800000, __float_as_int(v), ctrl, \
                                             0xf, 0xf, false);                         \
        v = fmaxf(v, __int_as_float(_t));                                              \
    }
    DPPSTEP(0x111) DPPSTEP(0x112) DPPSTEP(0x114) DPPSTEP(0x118) DPPSTEP(0x142) DPPSTEP(0x143)
#undef DPPSTEP
    return v;
}
__device__ __forceinline__ unsigned wave_red_min_u32(unsigned v) {
#define DPPSTEP(ctrl)                                                                   \
    {                                                                                   \
        unsigned _t = (unsigned)__builtin_amdgcn_update_dpp((int)0xFFFFFFFF, (int)v,    \
                                                            ctrl, 0xf, 0xf, false);     \
        v = v < _t ? v : _t;                                                            \
    }
    DPPSTEP(0x111) DPPSTEP(0x112) DPPSTEP(0x114) DPPSTEP(0x118) DPPSTEP(0x142) DPPSTEP(0x143)
#undef DPPSTEP
    return v;
}
__device__ __forceinline__ unsigned long long u64max(unsigned long long a, unsigned long long b) {
    return a > b ? a : b;
}
__device__ __forceinline__ unsigned u32min(unsigned a, unsigned b) { return a < b ? a : b; }

// ---------------- workspace layout (bytes); peak = 224,395,264 ------------------
static const size_t OFF_WBF   = 0;          // packed bf16 weights, 65536 elems (128 KB)
static const size_t OFF_STATS = 262144;     // 704 ch * 128 slots * 2 * 4B
static const size_t STATS_BYTES = 720896;
static const size_t OFF_AFF   = 1048576;    // per-layer scale/shift
static const size_t OFF_IDX0  = 2097152;    // 8*1024*32 ints
static const size_t OFF_IDX1  = 3145728;    // 8*1024*64 ints
static const size_t OFF_MX    = 5242880;    // 256*8192 fp32
static const size_t OFF_MN    = 13631488;
static const size_t OFF_Y0    = 22020096;   // bf16 X^T [NCOL][64]  (max 67 MB)
static const size_t OFF_Y1    = 90177536;   // bf16 X^T [NCOL][128] (max 134 MB)
static const size_t OFF_FEATT = 211812352;  // bf16 [8*8192][96] = 12.58 MB, overlaps Y1 tail
// (featTp last read in br1-L0; Y1 beyond 121.6 MB only written by br1-L1, which runs later.
//  Branch-interleave safety: y0 holds br0's activations until br0-L1 completes; the merged
//  [L2b0 | L0b1] launch then overwrites y0 with br1's L0 output — no aliasing.)

// ---------------- fused pre-kernel (256 threads/block):
// FPS (blocks 0..7) + feat transpose (8..1031) + weight pack (1032..1287) ----
__global__ __launch_bounds__(256) void fused_pre(
    const float* __restrict__ xyz, const float* __restrict__ feat,
    float* __restrict__ newxyz, unsigned short* __restrict__ ft,
    const float* __restrict__ w0, const float* __restrict__ w1, const float* __restrict__ w2,
    const float* __restrict__ w3, const float* __restrict__ w4, const float* __restrict__ w5,
    unsigned short* __restrict__ wb) {
    __shared__ union alignas(16) SM {
        struct {
            float ptsx[8200], ptsy[8200], ptsz[8200];
            float ldsM[16][3];
            float meanv[3];
            unsigned long long sKey[2][4];
            float cbuf[3072];  // selected centroids; written to global once at the end
        } f;
        float tile[64][65];
    } sm;
    const int tid = threadIdx.x;

    if (blockIdx.x >= 1032) {
        // ---- weight pack: w[M][K] f32 -> wb[Mp][Kp] bf16 (zero pad) ----
        int id = (int)(blockIdx.x - 1032) * 256 + tid;  // 0..65535
        const int psz[6] = {6144, 4096, 8192, 6144, 8192, 32768};
        const int Kp[6] = {96, 64, 64, 96, 64, 128};
        const int Ks[6] = {67, 64, 64, 67, 64, 128};
        const float* wp[6] = {w0, w1, w2, w3, w4, w5};
        int off = 0;
        for (int l = 0; l < 6; ++l) {
            if (id < off + psz[l]) {
                int e = id - off;
                int m = e / Kp[l], k = e - m * Kp[l];
                float v = (k < Ks[l]) ? wp[l][m * Ks[l] + k] : 0.f;
                wb[id] = f2bf(v);
                return;
            }
            off += psz[l];
        }
        return;
    }

    if (blockIdx.x >= 8) {
        // ---- featTp: [8][8192][96] bf16; c0..2 = xyz, c3..66 = feat, rest 0 ----
        int tb = (int)blockIdx.x - 8;  // 0..1023
        int b = tb >> 7;
        int j0 = (tb & 127) * 64;
#pragma unroll
        for (int i = 0; i < 16; ++i) {
            int e = i * 256 + tid;
            int c = e >> 6, j = e & 63;
            sm.tile[j][c] = feat[((size_t)b * 64 + c) * 8192 + j0 + j];
        }
        __syncthreads();
#pragma unroll
        for (int i = 0; i < 16; ++i) {
            int e = i * 256 + tid;
            int j = e >> 6, c = e & 63;
            ft[((size_t)(b * 8192 + j0 + j)) * 96 + 3 + c] = f2bf(sm.tile[j][c]);
        }
        if (tid < 64) {
            int j = tid;
            size_t base = ((size_t)(b * 8192 + j0 + j)) * 96;
            const float* xp = xyz + ((size_t)b * 8192 + j0 + j) * 3;
            ft[base + 0] = f2bf(xp[0]);
            ft[base + 1] = f2bf(xp[1]);
            ft[base + 2] = f2bf(xp[2]);
        } else if (tid < 128) {
            int j = tid - 64;
            size_t base = ((size_t)(b * 8192 + j0 + j)) * 96;
            for (int c = 67; c < 96; ++c) ft[base + c] = 0;
        }
        return;
    }

    // ---- FPS: 4 waves (1/SIMD), 32 pts/thread as 16 float2 pairs (R9/R10-proven;
    //      scalar form — two v_pk_f32 attempts both regressed, lever closed) ----
    const int b = blockIdx.x;
    const int t = tid;
    const int lane = t & 63, wv = t >> 6;  // wv 0..3
    const float* xb = xyz + (size_t)b * 8192 * 3;

    f32x2 px[16], py[16], pz[16], d[16];
#pragma unroll
    for (int k = 0; k < 16; ++k) {
        int q0 = t + 256 * (2 * k);
        int q1 = t + 256 * (2 * k + 1);
        px[k].x = xb[q0 * 3 + 0]; px[k].y = xb[q1 * 3 + 0];
        py[k].x = xb[q0 * 3 + 1]; py[k].y = xb[q1 * 3 + 1];
        pz[k].x = xb[q0 * 3 + 2]; pz[k].y = xb[q1 * 3 + 2];
        d[k].x = 1e10f; d[k].y = 1e10f;
        sm.f.ptsx[q0 + 1] = px[k].x; sm.f.ptsx[q1 + 1] = px[k].y;
        sm.f.ptsy[q0 + 1] = py[k].x; sm.f.ptsy[q1 + 1] = py[k].y;
        sm.f.ptsz[q0 + 1] = pz[k].x; sm.f.ptsz[q1 + 1] = pz[k].y;
    }
    // ---- mean: bit-identical replication of the v1 1024-partial tree ----
    {
        float sx[4], sy[4], sz[4];
#pragma unroll
        for (int m = 0; m < 4; ++m) {
            int u = (t + 256 * m + 1023) & 1023;
            float ax = 0.f, ay = 0.f, az = 0.f;
#pragma unroll
            for (int jj = 0; jj < 8; ++jj) {
                int ia = u + 1024 * jj;
                ax += xb[ia * 3 + 0]; ay += xb[ia * 3 + 1]; az += xb[ia * 3 + 2];
            }
            sx[m] = ax; sy[m] = ay; sz[m] = az;
        }
#pragma unroll
        for (int off = 32; off; off >>= 1) {
#pragma unroll
            for (int m = 0; m < 4; ++m) {
                sx[m] += __shfl_xor(sx[m], off, 64);
                sy[m] += __shfl_xor(sy[m], off, 64);
                sz[m] += __shfl_xor(sz[m], off, 64);
            }
        }
        if (lane == 0) {
#pragma unroll
            for (int m = 0; m < 4; ++m) {
                sm.f.ldsM[wv + 4 * m][0] = sx[m];
                sm.f.ldsM[wv + 4 * m][1] = sy[m];
                sm.f.ldsM[wv + 4 * m][2] = sz[m];
            }
        }
    }
    __syncthreads();
    if (t < 3) {
        float s = 0.f;
        for (int w = 0; w < 16; ++w) s += sm.f.ldsM[w][t];
        sm.f.meanv[t] = s * (1.f / 8192.f);
    }
    __syncthreads();
    float cx = sm.f.meanv[0], cy = sm.f.meanv[1], cz = sm.f.meanv[2];
    const float mmx = cx, mmy = cy, mmz = cz;  // mean point (pts idx 0), owned by t0
    float dm = 1e10f;
    if (t == 0) { sm.f.ptsx[0] = cx; sm.f.ptsy[0] = cy; sm.f.ptsz[0] = cz; }
    __syncthreads();

    for (int it = 0; it < 1024; ++it) {
        if (t == 0) {
            sm.f.cbuf[it * 3 + 0] = cx;
            sm.f.cbuf[it * 3 + 1] = cy;
            sm.f.cbuf[it * 3 + 2] = cz;
        }
        f32x2 c0, c1, c2, vm2;
        c0.x = cx; c0.y = cx; c1.x = cy; c1.y = cy; c2.x = cz; c2.y = cz;
        vm2.x = -1e30f; vm2.y = -1e30f;
        {
#pragma clang fp contract(off)
#pragma unroll
            for (int k = 0; k < 16; ++k) {
                f32x2 dx = px[k] - c0;
                f32x2 dy = py[k] - c1;
                f32x2 dz = pz[k] - c2;
                f32x2 dd = (dx * dx + dy * dy) + dz * dz;
                f32x2 nd = __builtin_elementwise_min(d[k], dd);
                d[k] = nd;
                vm2 = __builtin_elementwise_max(vm2, nd);
            }
        }
        float vmax = fmaxf(vm2.x, vm2.y);
        if (t == 0) {
            float dx = __fsub_rn(mmx, cx);
            float dy = __fsub_rn(mmy, cy);
            float dz = __fsub_rn(mmz, cz);
            float dd = __fadd_rn(__fadd_rn(__fmul_rn(dx, dx), __fmul_rn(dy, dy)), __fmul_rn(dz, dz));
            dm = fminf(dm, dd);
            vmax = fmaxf(vmax, dm);
        }
        float wm = wave_red_max_f32(vmax);
        float bmaxw = __int_as_float(__builtin_amdgcn_readlane(__float_as_int(wm), 63));
        unsigned m2[16];
#pragma unroll
        for (int k = 0; k < 16; ++k) {
            unsigned i0 = (d[k].x == bmaxw) ? (unsigned)(t + 256 * (2 * k) + 1) : 0xFFFFFFFFu;
            unsigned i1 = (d[k].y == bmaxw) ? (unsigned)(t + 256 * (2 * k + 1) + 1) : 0xFFFFFFFFu;
            m2[k] = u32min(i0, i1);
        }
#pragma unroll
        for (int s = 8; s; s >>= 1)
#pragma unroll
            for (int k = 0; k < s; ++k) m2[k] = u32min(m2[k], m2[k + s]);
        unsigned mi = m2[0];
        if (t == 0 && dm == bmaxw) mi = 0u;
        unsigned wmin = wave_red_min_u32(mi);
        unsigned miw = (unsigned)__builtin_amdgcn_readlane((int)wmin, 63);
        int par = it & 1;
        if (lane == 0)
            sm.f.sKey[par][wv] = ((unsigned long long)__float_as_uint(bmaxw) << 32) |
                                 (unsigned long long)(8192u - miw);
        __syncthreads();  // the ONLY barrier per iteration (parity-double-buffered slots)
        unsigned long long ka[4];
#pragma unroll
        for (int i = 0; i < 4; ++i) ka[i] = sm.f.sKey[par][i];  // same-address broadcasts
        unsigned long long kk = u64max(u64max(ka[0], ka[1]), u64max(ka[2], ka[3]));
        int far = 8192 - (int)(unsigned)(kk & 0xffffffffull);
        cx = sm.f.ptsx[far];  // uniform LDS broadcast
        cy = sm.f.ptsy[far];
        cz = sm.f.ptsz[far];
    }
    __syncthreads();
    float* ob = newxyz + (size_t)b * 3072;
#pragma unroll
    for (int i = 0; i < 12; ++i) ob[t + 256 * i] = sm.f.cbuf[t + 256 * i];
}

// ---------------- merged ball query: blocks 0..2047 br0 (K=32), 2048..4095 br1 --
__global__ void ball_query2(const float* __restrict__ xyz, const float* __restrict__ newxyz,
                            int* __restrict__ idx0, int* __restrict__ idx1) {
    int bid = blockIdx.x;
    int br = (bid >= 2048);
    int K = br ? 64 : 32;
    float r2 = br ? (0.8f * 0.8f) : (0.4f * 0.4f);
    int* idxout = br ? idx1 : idx0;
    int wid = (((bid & 2047) * 256) + threadIdx.x) >> 6;  // query id, 0..8191
    int lane = threadIdx.x & 63;
    int b = wid >> 10;
    const float* q = newxyz + (size_t)wid * 3;
    float qx = q[0], qy = q[1], qz = q[2];
    const float* xb = xyz + (size_t)b * 8192 * 3;
    int* out = idxout + (size_t)wid * K;
    int count = 0;
    int first = 0;
    for (int base = 0; base < 8192 && count < K; base += 64) {
        int j = base + lane;
        float dx = __fsub_rn(xb[j * 3 + 0], qx);
        float dy = __fsub_rn(xb[j * 3 + 1], qy);
        float dz = __fsub_rn(xb[j * 3 + 2], qz);
        float d2 = __fadd_rn(__fadd_rn(__fmul_rn(dx, dx), __fmul_rn(dy, dy)), __fmul_rn(dz, dz));
        bool in = d2 < r2;
        unsigned long long m = __ballot(in);
        if (count == 0 && m) first = base + __ffsll((long long)m) - 1;
        if (in) {
            int pos = count + __popcll(m & ((1ull << lane) - 1ull));
            if (pos < K) out[pos] = j;
        }
        count += __popcll(m);
    }
    if (count < K) {
        int fillv = (count > 0) ? first : 0;
        for (int p = count + lane; p < K; p += 64) out[p] = fillv;
    }
}

// ---------------- MFMA GEMM body (device fn; shared by solo + merged kernels) ---
// Fragment-major conflict-free LDS staging (R8-proven). smemRaw must be 16B-aligned,
// sized NCHUNK*16 + NT*64*4 bytes.
template <int Mp, int Kp, int IN_MODE, int OUT_MODE, int KSH, int NT>
__device__ __forceinline__ void gemm_body(
    int bid, char* smemRaw,
    const unsigned short* __restrict__ Wb, const unsigned short* __restrict__ Xin,
    const float* __restrict__ aff, const int* __restrict__ idx,
    const unsigned short* __restrict__ ftp, const float* __restrict__ newxyz,
    unsigned short* __restrict__ Yout, float* __restrict__ MX, float* __restrict__ MN,
    float* __restrict__ statS, float* __restrict__ statQ) {
    constexpr int MT = Mp / 64;
    constexpr int KS = Kp / 32;
    constexpr int NC = NT * 16;              // cols per block
    constexpr int NCHUNK = NT * KS * 64;     // 16B chunks in Bs
    unsigned short* Bs = (unsigned short*)smemRaw;
    float* sAux = (float*)(smemRaw + (size_t)NCHUNK * 16);
    int* sAuxI = (int*)sAux;

    const int tid = threadIdx.x;
    const int w = tid >> 6;
    const int lane = tid & 63;
    const int n = lane & 15;
    const int quad = lane >> 4;
    const int rbase = w * (Mp / 4);
    const long col0 = (long)bid * NC;

    short8 a[MT][KS];
#pragma unroll
    for (int mt = 0; mt < MT; ++mt)
#pragma unroll
        for (int ks = 0; ks < KS; ++ks)
            a[mt][ks] = *(const short8*)(Wb + (size_t)(rbase + mt * 16 + n) * Kp + ks * 32 + quad * 8);

    if constexpr (IN_MODE == 0) {
        for (int c = tid; c < NC; c += 256) {
            long colg = col0 + c;
            sAuxI[c] = idx[colg];
            long sk = colg >> KSH;
            sAux[NC + c] = newxyz[sk * 3 + 0];
            sAux[2 * NC + c] = newxyz[sk * 3 + 1];
            sAux[3 * NC + c] = newxyz[sk * 3 + 2];
        }
    } else {
        if (tid < 2 * Kp) sAux[tid] = aff[tid];
    }
    __syncthreads();

    // ---- Phase 1: build B-tile in LDS, chunk p = i*256+tid (lane-sequential) ----
#pragma unroll
    for (int i = 0; i < NCHUNK / 256; ++i) {
        int p = i * 256 + tid;
        int pl = p & 63;
        int pn = pl & 15;
        int pq = pl >> 4;
        int rest = p >> 6;  // pnt*KS + pks
        int pks = rest % KS;
        int pnt = rest / KS;
        int col = pnt * 16 + pn;
        int kc = pks * 4 + pq;  // 16B chunk index along K
        short8 v;
        if constexpr (IN_MODE == 0) {
            const int bb = (int)(col0 >> (KSH + 10));
            int j = sAuxI[col];
            v = *(const short8*)(ftp + ((long)(bb * 8192 + j)) * 96 + kc * 8);
            if (kc == 0) {  // rel-xyz patch: channels 0..2
                v[0] = (short)f2bf(bf2f((unsigned short)v[0]) - sAux[NC + col]);
                v[1] = (short)f2bf(bf2f((unsigned short)v[1]) - sAux[2 * NC + col]);
                v[2] = (short)f2bf(bf2f((unsigned short)v[2]) - sAux[3 * NC + col]);
            }
        } else {
            short8 raw = *(const short8*)(Xin + (col0 + col) * (long)Kp + kc * 8);
#pragma unroll
            for (int e = 0; e < 8; ++e) {
                float xf = bf2f((unsigned short)raw[e]);
                xf = fmaxf(fmaf(xf, sAux[kc * 8 + e], sAux[Kp + kc * 8 + e]), 0.f);
                v[e] = (short)f2bf(xf);
            }
        }
        *(short8*)(&Bs[p * 8]) = v;
    }
    __syncthreads();

    // ---- Phase 2: MFMA from LDS fragments (lane-sequential ds_read_b128) ----
    f32x4 acc[MT][NT];
#pragma unroll
    for (int mt = 0; mt < MT; ++mt)
#pragma unroll
        for (int nt = 0; nt < NT; ++nt)
#pragma unroll
            for (int r = 0; r < 4; ++r) acc[mt][nt][r] = 0.f;

#pragma unroll
    for (int ks = 0; ks < KS; ++ks) {
#pragma unroll
        for (int nt = 0; nt < NT; ++nt) {
            short8 bfr = *(const short8*)(&Bs[((nt * KS + ks) * 64 + lane) * 8]);
#pragma unroll
            for (int mt = 0; mt < MT; ++mt)
                acc[mt][nt] = __builtin_amdgcn_mfma_f32_16x16x32_bf16(a[mt][ks], bfr, acc[mt][nt], 0, 0, 0);
        }
    }

    // ---- stats: per-channel sum / sumsq ----
    const int slot = bid & 127;
#pragma unroll
    for (int mt = 0; mt < MT; ++mt)
#pragma unroll
        for (int r = 0; r < 4; ++r) {
            float s = 0.f, q = 0.f;
#pragma unroll
            for (int nt = 0; nt < NT; ++nt) {
                float v = acc[mt][nt][r];
                s += v;
                q = fmaf(v, v, q);
            }
#pragma unroll
            for (int off = 1; off < 16; off <<= 1) {
                s += __shfl_xor(s, off, 16);
                q += __shfl_xor(q, off, 16);
            }
            if (n == 0) {
                int ch = rbase + mt * 16 + quad * 4 + r;
                atomicAdd(statS + (size_t)ch * 128 + slot, s);
                atomicAdd(statQ + (size_t)ch * 128 + slot, q);
            }
        }

    if constexpr (OUT_MODE == 0) {
#pragma unroll
        for (int mt = 0; mt < MT; ++mt)
#pragma unroll
            for (int nt = 0; nt < NT; ++nt) {
                long col = col0 + nt * 16 + n;
                unsigned p0 = f2bf(acc[mt][nt][0]) | ((unsigned)f2bf(acc[mt][nt][1]) << 16);
                unsigned p1 = f2bf(acc[mt][nt][2]) | ((unsigned)f2bf(acc[mt][nt][3]) << 16);
                uint2 st; st.x = p0; st.y = p1;
                *(uint2*)(Yout + col * Mp + rbase + mt * 16 + quad * 4) = st;
            }
    } else {
        constexpr int GRP = (1 << KSH) / 16;  // n-tiles per K-sample group (2 or 4)
        constexpr int NG = NT / GRP;          // groups per block
#pragma unroll
        for (int mt = 0; mt < MT; ++mt)
#pragma unroll
            for (int r = 0; r < 4; ++r) {
#pragma unroll
                for (int gh = 0; gh < NG; ++gh) {
                    float mx = acc[mt][GRP * gh][r], mn = acc[mt][GRP * gh][r];
#pragma unroll
                    for (int e = 1; e < GRP; ++e) {
                        mx = fmaxf(mx, acc[mt][GRP * gh + e][r]);
                        mn = fminf(mn, acc[mt][GRP * gh + e][r]);
                    }
#pragma unroll
                    for (int off = 1; off < 16; off <<= 1) {
                        mx = fmaxf(mx, __shfl_xor(mx, off, 16));
                        mn = fminf(mn, __shfl_xor(mn, off, 16));
                    }
                    if (n == 0) {
                        int ch = rbase + mt * 16 + quad * 4 + r;
                        long g = (col0 >> KSH) + gh;
                        MX[(long)ch * 8192 + g] = mx;
                        MN[(long)ch * 8192 + g] = mn;
                    }
                }
            }
    }
}

// ---------------- solo gemm kernel wrapper --------------------------------------
template <int Mp, int Kp, int IN_MODE, int OUT_MODE, int KSH, int NT>
__global__ __launch_bounds__(256) void gemm_mfma(
    const unsigned short* __restrict__ Wb, const unsigned short* __restrict__ Xin,
    const float* __restrict__ aff, const int* __restrict__ idx,
    const unsigned short* __restrict__ ftp, const float* __restrict__ newxyz,
    unsigned short* __restrict__ Yout, float* __restrict__ MX, float* __restrict__ MN,
    float* __restrict__ statS, float* __restrict__ statQ) {
    constexpr int SMEM = NT * (Kp / 32) * 64 * 16 + NT * 64 * 4;
    __shared__ alignas(16) char smem[SMEM];
    gemm_body<Mp, Kp, IN_MODE, OUT_MODE, KSH, NT>(blockIdx.x, smem, Wb, Xin, aff, idx, ftp,
                                                  newxyz, Yout, MX, MN, statS, statQ);
}

// ---------------- merged: L2-br0 (blocks < nA) | L0-br1 (blocks >= nA) ----------
__global__ __launch_bounds__(256) void gemm_l2b0_l0b1(
    const unsigned short* __restrict__ WbA, const unsigned short* __restrict__ XinA,
    const float* __restrict__ affA, float* __restrict__ MXA, float* __restrict__ MNA,
    float* __restrict__ sSA, float* __restrict__ sQA,
    const unsigned short* __restrict__ WbB, const int* __restrict__ idxB,
    const unsigned short* __restrict__ ftpB, const float* __restrict__ newxyzB,
    unsigned short* __restrict__ YoutB, float* __restrict__ sSB, float* __restrict__ sQB,
    int nA) {
    extern __shared__ char smem[];
    if ((int)blockIdx.x < nA)
        gemm_body<128, 64, 1, 1, 5, 8>((int)blockIdx.x, smem, WbA, XinA, affA, nullptr, nullptr,
                                       nullptr, nullptr, MXA, MNA, sSA, sQA);
    else
        gemm_body<64, 96, 0, 0, 6, 16>((int)blockIdx.x - nA, smem, WbB, nullptr, nullptr, idxB,
                                       ftpB, newxyzB, YoutB, nullptr, nullptr, sSB, sQB);
}

// ---------------- merged: L1-br1 (blocks < nA) | final_out-br0 (blocks >= nA) ---
__global__ __launch_bounds__(256) void gemm_l1b1_fo0(
    const unsigned short* __restrict__ Wb, const unsigned short* __restrict__ Xin,
    const float* __restrict__ aff, unsigned short* __restrict__ Yout,
    float* __restrict__ sS, float* __restrict__ sQ,
    const float* __restrict__ MX, const float* __restrict__ MN,
    const float* __restrict__ affF, float* __restrict__ out1, int nA) {
    extern __shared__ char smem[];
    if ((int)blockIdx.x < nA) {
        gemm_body<128, 64, 1, 0, 6, 8>((int)blockIdx.x, smem, Wb, Xin, aff, nullptr, nullptr,
                                       nullptr, Yout, nullptr, nullptr, sS, sQ);
    } else {
        long i = (long)((int)blockIdx.x - nA) * 256 + threadIdx.x;  // over 128*8192
        int c = (int)(i >> 13);
        int gidx = (int)(i & 8191);
        int b = gidx >> 10, s = gidx & 1023;
        float sc = affF[c], sh = affF[128 + c];
        float v = fmaxf(fmaxf(sc * MX[i] + sh, sc * MN[i] + sh), 0.f);
        out1[((long)b * 384 + c) * 1024 + s] = v;
    }
}

// ---------------- finalize BN constants -----------------------------------------
__global__ void finalize_kernel(const float* __restrict__ sS, const float* __restrict__ sQ,
                                const float* __restrict__ g, const float* __restrict__ b,
                                float* __restrict__ aff, int C, float invCount) {
    int c = threadIdx.x + blockIdx.x * blockDim.x;
    if (c >= C) return;
    float s = 0.f, q = 0.f;
    for (int k = 0; k < 128; ++k) { s += sS[c * 128 + k]; q += sQ[c * 128 + k]; }
    float mean = s * invCount;
    float var = fmaxf(q * invCount - mean * mean, 0.f);
    float sc = g[c] / sqrtf(var + 1e-5f);
    float sh = b[c] - mean * sc;
    aff[c] = sc;
    aff[C + c] = sh;
}

// two-layer finalize in one launch (block 0 -> set0, block 1 -> set1)
__global__ void finalize2_kernel(const float* __restrict__ sS0, const float* __restrict__ sQ0,
                                 const float* __restrict__ g0, const float* __restrict__ b0,
                                 float* __restrict__ aff0, int C0, float ic0,
                                 const float* __restrict__ sS1, const float* __restrict__ sQ1,
                                 const float* __restrict__ g1, const float* __restrict__ b1,
                                 float* __restrict__ aff1, int C1, float ic1) {
    const float* sS = blockIdx.x ? sS1 : sS0;
    const float* sQ = blockIdx.x ? sQ1 : sQ0;
    const float* g = blockIdx.x ? g1 : g0;
    const float* b = blockIdx.x ? b1 : b0;
    float* aff = blockIdx.x ? aff1 : aff0;
    int C = blockIdx.x ? C1 : C0;
    float ic = blockIdx.x ? ic1 : ic0;
    int c = threadIdx.x;
    if (c >= C) return;
    float s = 0.f, q = 0.f;
    for (int k = 0; k < 128; ++k) { s += sS[c * 128 + k]; q += sQ[c * 128 + k]; }
    float mean = s * ic;
    float var = fmaxf(q * ic - mean * mean, 0.f);
    float sc = g[c] / sqrtf(var + 1e-5f);
    float sh = b[c] - mean * sc;
    aff[c] = sc;
    aff[C + c] = sh;
}

// ---------------- final output (br1) --------------------------------------------
__global__ void final_out_kernel(const float* __restrict__ MX, const float* __restrict__ MN,
                                 const float* __restrict__ aff, float* __restrict__ out1,
                                 int Cout, int cOff) {
    long i = (long)blockIdx.x * 256 + threadIdx.x;
    int c = (int)(i >> 13);
    int gidx = (int)(i & 8191);
    int b = gidx >> 10, s = gidx & 1023;
    float sc = aff[c], sh = aff[Cout + c];
    float v = fmaxf(fmaxf(sc * MX[i] + sh, sc * MN[i] + sh), 0.f);
    out1[((long)b * 384 + cOff + c) * 1024 + s] = v;
}

// ---------------- host ----------------------------------------------------------
extern "C" void kernel_launch(void* const* d_in, const int* in_sizes, int n_in,
                              void* d_out, int out_size, void* d_ws, size_t ws_size,
                              hipStream_t stream) {
    const float* xyz = (const float*)d_in[0];
    const float* feat = (const float*)d_in[1];
    const float *W[6], *G[6], *Bi[6];
    for (int l = 0; l < 6; ++l) {
        W[l] = (const float*)d_in[2 + l * 3];
        G[l] = (const float*)d_in[3 + l * 3];
        Bi[l] = (const float*)d_in[4 + l * 3];
    }
    char* ws = (char*)d_ws;
    float* out0 = (float*)d_out;
    float* out1 = (float*)d_out + 24576;

    unsigned short* wb = (unsigned short*)(ws + OFF_WBF);
    float* stats = (float*)(ws + OFF_STATS);
    float* affine = (float*)(ws + OFF_AFF);
    int* idx0 = (int*)(ws + OFF_IDX0);
    int* idx1 = (int*)(ws + OFF_IDX1);
    float* mx = (float*)(ws + OFF_MX);
    float* mn = (float*)(ws + OFF_MN);
    unsigned short* y0 = (unsigned short*)(ws + OFF_Y0);
    unsigned short* y1 = (unsigned short*)(ws + OFF_Y1);
    unsigned short* ftp = (unsigned short*)(ws + OFF_FEATT);

    hipMemsetAsync(stats, 0, STATS_BYTES, stream);
    fused_pre<<<1288, 256, 0, stream>>>(xyz, feat, out0, ftp, W[0], W[1], W[2], W[3], W[4],
                                        W[5], wb);
    ball_query2<<<4096, 256, 0, stream>>>(xyz, out0, idx0, idx1);

    const int wOff[6] = {0, 6144, 10240, 18432, 24576, 32768};
    int stOff[6], afOff[6];
    {
        const int Cs[6] = {64, 64, 128, 64, 128, 256};
        int so = 0, ao = 0;
        for (int l = 0; l < 6; ++l) {
            stOff[l] = so; so += Cs[l] * 256;
            afOff[l] = ao; ao += Cs[l] * 2;
        }
    }
    const float ic0 = 1.f / (float)(8L * 1024 * 32);  // br0 NCOL
    const float ic1 = 1.f / (float)(8L * 1024 * 64);  // br1 NCOL

    // ---- br0 L0, L1 ----
    gemm_mfma<64, 96, 0, 0, 5, 16><<<1024, 256, 0, stream>>>(
        wb + wOff[0], nullptr, nullptr, idx0, ftp, out0, y0, nullptr, nullptr,
        stats + stOff[0], stats + stOff[0] + 64 * 128);
    finalize_kernel<<<1, 256, 0, stream>>>(stats + stOff[0], stats + stOff[0] + 64 * 128,
                                           G[0], Bi[0], affine + afOff[0], 64, ic0);
    gemm_mfma<64, 64, 1, 0, 5, 16><<<1024, 256, 0, stream>>>(
        wb + wOff[1], y0, affine + afOff[0], nullptr, nullptr, nullptr, y1, nullptr,
        nullptr, stats + stOff[1], stats + stOff[1] + 64 * 128);
    finalize_kernel<<<1, 256, 0, stream>>>(stats + stOff[1], stats + stOff[1] + 64 * 128,
                                           G[1], Bi[1], affine + afOff[1], 64, ic0);

    // ---- merged: L2-br0 (2048 blocks) | L0-br1 (2048 blocks) ----
    // LDS: max(NT8*KS2, NT16*KS3) staging = 53248 B dynamic
    gemm_l2b0_l0b1<<<4096, 256, 53248, stream>>>(
        wb + wOff[2], y1, affine + afOff[1], mx, mn, stats + stOff[2],
        stats + stOff[2] + 128 * 128, wb + wOff[3], idx1, ftp, out0, y0, stats + stOff[3],
        stats + stOff[3] + 64 * 128, 2048);
    finalize2_kernel<<<2, 256, 0, stream>>>(
        stats + stOff[2], stats + stOff[2] + 128 * 128, G[2], Bi[2], affine + afOff[2], 128, ic0,
        stats + stOff[3], stats + stOff[3] + 64 * 128, G[3], Bi[3], affine + afOff[3], 64, ic1);

    // ---- merged: L1-br1 (4096 blocks) | final_out-br0 (4096 blocks) ----
    gemm_l1b1_fo0<<<8192, 256, 18432, stream>>>(
        wb + wOff[4], y0, affine + afOff[3], y1, stats + stOff[4], stats + stOff[4] + 128 * 128,
        mx, mn, affine + afOff[2], out1, 4096);
    finalize_kernel<<<1, 256, 0, stream>>>(stats + stOff[4], stats + stOff[4] + 128 * 128,
                                           G[4], Bi[4], affine + afOff[4], 128, ic1);

    // ---- br1 L2 + finalize + final_out ----
    gemm_mfma<256, 128, 1, 1, 6, 4><<<8192, 256, 0, stream>>>(
        wb + wOff[5], y1, affine + afOff[4], nullptr, nullptr, nullptr, nullptr, mx, mn,
        stats + stOff[5], stats + stOff[5] + 256 * 128);
    finalize_kernel<<<1, 256, 0, stream>>>(stats + stOff[5], stats + stOff[5] + 256 * 128,
                                           G[5], Bi[5], affine + afOff[5], 256, ic1);
    final_out_kernel<<<(256 * 8192) / 256, 256, 0, stream>>>(mx, mn, affine + afOff[5], out1,
                                                             256, 128);
}

// Round 13
// 1592.860 us; speedup vs baseline: 1.0984x; 1.0271x over previous
//
#include <hip/hip_runtime.h>
#include <hip/hip_bf16.h>
#include <cstdint>

// B=8, N=8192, S=1024, C=64
// branch0: r=0.4, K=32, layers 64x67, 64x64, 128x64
// branch1: r=0.8, K=64, layers 64x67, 128x64, 256x128

typedef __attribute__((ext_vector_type(8))) short short8;
typedef __attribute__((ext_vector_type(4))) float f32x4;
typedef __attribute__((ext_vector_type(2))) float f32x2;

__device__ __forceinline__ float bf2f(unsigned short u) {
    return __uint_as_float(((unsigned)u) << 16);
}
__device__ __forceinline__ unsigned short f2bf(float f) {
    unsigned u = __float_as_uint(f);
    return (unsigned short)((u + 0x7fffu + ((u >> 16) & 1u)) >> 16);  // RNE
}

// Wave-64 reductions on the VALU pipe via DPP (rocPRIM pattern): result in lane 63.
__device__ __forceinline__ float wave_red_max_f32(float v) {
#define DPPSTEP(ctrl)                                                                  \
    {                                                                                  \
        int _t = __builtin_amdgcn_update_dpp((int)0xFF800000, __float_as_int(v), ctrl, \
                                             0xf, 0xf, false);                         \
        v = fmaxf(v, __int_as_float(_t));                                              \
    }
    DPPSTEP(0x111) DPPSTEP(0x112) DPPSTEP(0x114) DPPSTEP(0x118) DPPSTEP(0x142) DPPSTEP(0x143)
#undef DPPSTEP
    return v;
}
__device__ __forceinline__ unsigned wave_red_min_u32(unsigned v) {
#define DPPSTEP(ctrl)                                                                   \
    {                                                                                   \
        unsigned _t = (unsigned)__builtin_amdgcn_update_dpp((int)0xFFFFFFFF, (int)v,    \
                                                            ctrl, 0xf, 0xf, false);     \
        v = v < _t ? v : _t;                                                            \
    }
    DPPSTEP(0x111) DPPSTEP(0x112) DPPSTEP(0x114) DPPSTEP(0x118) DPPSTEP(0x142) DPPSTEP(0x143)
#undef DPPSTEP
    return v;
}
__device__ __forceinline__ unsigned long long u64max(unsigned long long a, unsigned long long b) {
    return a > b ? a : b;
}
__device__ __forceinline__ unsigned u32min(unsigned a, unsigned b) { return a < b ? a : b; }

// ---------------- workspace layout (bytes); peak = 224,395,264 ------------------
static const size_t OFF_WBF   = 0;          // packed bf16 weights, 65536 elems (128 KB)
static const size_t OFF_STATS = 262144;     // 704 ch * 128 slots * 2 * 4B
static const size_t STATS_BYTES = 720896;
static const size_t OFF_AFF   = 1048576;    // per-layer scale/shift
static const size_t OFF_IDX0  = 2097152;    // 8*1024*32 ints
static const size_t OFF_IDX1  = 3145728;    // 8*1024*64 ints
static const size_t OFF_MX    = 5242880;    // 256*8192 fp32
static const size_t OFF_MN    = 13631488;
static const size_t OFF_Y0    = 22020096;   // bf16 X^T [NCOL][64]  (max 67 MB)
static const size_t OFF_Y1    = 90177536;   // bf16 X^T [NCOL][128] (max 134 MB)
static const size_t OFF_FEATT = 211812352;  // bf16 [8*8192][96] = 12.58 MB, overlaps Y1 tail
// (featTp last read in br1-L0; Y1 beyond 121.6 MB only written by br1-L1, which runs later.
//  Branch-interleave safety: y0 holds br0's activations until br0-L1 completes; the merged
//  [L2b0 | L0b1] launch then overwrites y0 with br1's L0 output — no aliasing.)

// ---------------- fused pre-kernel (256 threads/block):
// FPS (blocks 0..7) + feat transpose (8..1031) + weight pack (1032..1287) ----
__global__ __launch_bounds__(256) void fused_pre(
    const float* __restrict__ xyz, const float* __restrict__ feat,
    float* __restrict__ newxyz, unsigned short* __restrict__ ft,
    const float* __restrict__ w0, const float* __restrict__ w1, const float* __restrict__ w2,
    const float* __restrict__ w3, const float* __restrict__ w4, const float* __restrict__ w5,
    unsigned short* __restrict__ wb) {
    __shared__ union alignas(16) SM {
        struct {
            float ptsx[8200], ptsy[8200], ptsz[8200];
            float ldsM[16][3];
            float meanv[3];
            alignas(16) unsigned long long sKey[2][4];
            float cbuf[3072];  // selected centroids; written to global once at the end
        } f;
        float tile[64][65];
    } sm;
    const int tid = threadIdx.x;

    if (blockIdx.x >= 1032) {
        // ---- weight pack: w[M][K] f32 -> wb[Mp][Kp] bf16 (zero pad) ----
        int id = (int)(blockIdx.x - 1032) * 256 + tid;  // 0..65535
        const int psz[6] = {6144, 4096, 8192, 6144, 8192, 32768};
        const int Kp[6] = {96, 64, 64, 96, 64, 128};
        const int Ks[6] = {67, 64, 64, 67, 64, 128};
        const float* wp[6] = {w0, w1, w2, w3, w4, w5};
        int off = 0;
        for (int l = 0; l < 6; ++l) {
            if (id < off + psz[l]) {
                int e = id - off;
                int m = e / Kp[l], k = e - m * Kp[l];
                float v = (k < Ks[l]) ? wp[l][m * Ks[l] + k] : 0.f;
                wb[id] = f2bf(v);
                return;
            }
            off += psz[l];
        }
        return;
    }

    if (blockIdx.x >= 8) {
        // ---- featTp: [8][8192][96] bf16; c0..2 = xyz, c3..66 = feat, rest 0 ----
        int tb = (int)blockIdx.x - 8;  // 0..1023
        int b = tb >> 7;
        int j0 = (tb & 127) * 64;
#pragma unroll
        for (int i = 0; i < 16; ++i) {
            int e = i * 256 + tid;
            int c = e >> 6, j = e & 63;
            sm.tile[j][c] = feat[((size_t)b * 64 + c) * 8192 + j0 + j];
        }
        __syncthreads();
#pragma unroll
        for (int i = 0; i < 16; ++i) {
            int e = i * 256 + tid;
            int j = e >> 6, c = e & 63;
            ft[((size_t)(b * 8192 + j0 + j)) * 96 + 3 + c] = f2bf(sm.tile[j][c]);
        }
        if (tid < 64) {
            int j = tid;
            size_t base = ((size_t)(b * 8192 + j0 + j)) * 96;
            const float* xp = xyz + ((size_t)b * 8192 + j0 + j) * 3;
            ft[base + 0] = f2bf(xp[0]);
            ft[base + 1] = f2bf(xp[1]);
            ft[base + 2] = f2bf(xp[2]);
        } else if (tid < 128) {
            int j = tid - 64;
            size_t base = ((size_t)(b * 8192 + j0 + j)) * 96;
            for (int c = 67; c < 96; ++c) ft[base + c] = 0;
        }
        return;
    }

    // ---- FPS: 4 waves (1/SIMD), 32 pts/thread as 16 float2 pairs.
    // In-loop running argmax (strict >, ascending own indices == first-occurrence
    // among float-equal ties) removes the 79-instr post-broadcast tie-scan from
    // the serial chain — at 1 wave/SIMD that latency was unhidden. ----
    const int b = blockIdx.x;
    const int t = tid;
    const int lane = t & 63, wv = t >> 6;  // wv 0..3
    const float* xb = xyz + (size_t)b * 8192 * 3;

    f32x2 px[16], py[16], pz[16], d[16];
#pragma unroll
    for (int k = 0; k < 16; ++k) {
        int q0 = t + 256 * (2 * k);
        int q1 = t + 256 * (2 * k + 1);
        px[k].x = xb[q0 * 3 + 0]; px[k].y = xb[q1 * 3 + 0];
        py[k].x = xb[q0 * 3 + 1]; py[k].y = xb[q1 * 3 + 1];
        pz[k].x = xb[q0 * 3 + 2]; pz[k].y = xb[q1 * 3 + 2];
        d[k].x = 1e10f; d[k].y = 1e10f;
        sm.f.ptsx[q0 + 1] = px[k].x; sm.f.ptsx[q1 + 1] = px[k].y;
        sm.f.ptsy[q0 + 1] = py[k].x; sm.f.ptsy[q1 + 1] = py[k].y;
        sm.f.ptsz[q0 + 1] = pz[k].x; sm.f.ptsz[q1 + 1] = pz[k].y;
    }
    // ---- mean: bit-identical replication of the v1 1024-partial tree ----
    {
        float sx[4], sy[4], sz[4];
#pragma unroll
        for (int m = 0; m < 4; ++m) {
            int u = (t + 256 * m + 1023) & 1023;
            float ax = 0.f, ay = 0.f, az = 0.f;
#pragma unroll
            for (int jj = 0; jj < 8; ++jj) {
                int ia = u + 1024 * jj;
                ax += xb[ia * 3 + 0]; ay += xb[ia * 3 + 1]; az += xb[ia * 3 + 2];
            }
            sx[m] = ax; sy[m] = ay; sz[m] = az;
        }
#pragma unroll
        for (int off = 32; off; off >>= 1) {
#pragma unroll
            for (int m = 0; m < 4; ++m) {
                sx[m] += __shfl_xor(sx[m], off, 64);
                sy[m] += __shfl_xor(sy[m], off, 64);
                sz[m] += __shfl_xor(sz[m], off, 64);
            }
        }
        if (lane == 0) {
#pragma unroll
            for (int m = 0; m < 4; ++m) {
                sm.f.ldsM[wv + 4 * m][0] = sx[m];
                sm.f.ldsM[wv + 4 * m][1] = sy[m];
                sm.f.ldsM[wv + 4 * m][2] = sz[m];
            }
        }
    }
    __syncthreads();
    if (t < 3) {
        float s = 0.f;
        for (int w = 0; w < 16; ++w) s += sm.f.ldsM[w][t];
        sm.f.meanv[t] = s * (1.f / 8192.f);
    }
    __syncthreads();
    float cx = sm.f.meanv[0], cy = sm.f.meanv[1], cz = sm.f.meanv[2];
    const float mmx = cx, mmy = cy, mmz = cz;  // mean point (pts idx 0), owned by t0
    float dm = 1e10f;
    if (t == 0) { sm.f.ptsx[0] = cx; sm.f.ptsy[0] = cy; sm.f.ptsz[0] = cz; }
    __syncthreads();

    for (int it = 0; it < 1024; ++it) {
        if (t == 0) {
            sm.f.cbuf[it * 3 + 0] = cx;
            sm.f.cbuf[it * 3 + 1] = cy;
            sm.f.cbuf[it * 3 + 2] = cz;
        }
        f32x2 c0, c1, c2;
        c0.x = cx; c0.y = cx; c1.x = cy; c1.y = cy; c2.x = cz; c2.y = cz;
        float bv = -1e30f;   // running max over own points
        unsigned bi = 0u;    // its first-occurrence own index
        {
#pragma clang fp contract(off)
#pragma unroll
            for (int k = 0; k < 16; ++k) {
                f32x2 dx = px[k] - c0;
                f32x2 dy = py[k] - c1;
                f32x2 dz = pz[k] - c2;
                f32x2 dd = (dx * dx + dy * dy) + dz * dz;
                f32x2 nd = __builtin_elementwise_min(d[k], dd);
                d[k] = nd;
                // ascending own-index order (q0 then q1, k ascending) + strict >
                // == smallest index among float-equal maxima
                bool g0 = nd.x > bv;
                bv = fmaxf(bv, nd.x);
                bi = g0 ? (unsigned)(t + 256 * (2 * k) + 1) : bi;
                bool g1 = nd.y > bv;
                bv = fmaxf(bv, nd.y);
                bi = g1 ? (unsigned)(t + 256 * (2 * k + 1) + 1) : bi;
            }
        }
        if (t == 0) {
            float dx = __fsub_rn(mmx, cx);
            float dy = __fsub_rn(mmy, cy);
            float dz = __fsub_rn(mmz, cz);
            float dd = __fadd_rn(__fadd_rn(__fmul_rn(dx, dx), __fmul_rn(dy, dy)), __fmul_rn(dz, dz));
            dm = fminf(dm, dd);
            bv = fmaxf(bv, dm);
        }
        float wm = wave_red_max_f32(bv);
        float bmaxw = __int_as_float(__builtin_amdgcn_readlane(__float_as_int(wm), 63));
        unsigned mi = (bv == bmaxw) ? bi : 0xFFFFFFFFu;
        if (t == 0 && dm == bmaxw) mi = 0u;  // mean point (idx 0) wins all ties
        unsigned wmin = wave_red_min_u32(mi);
        unsigned miw = (unsigned)__builtin_amdgcn_readlane((int)wmin, 63);
        int par = it & 1;
        if (lane == 0)
            sm.f.sKey[par][wv] = ((unsigned long long)__float_as_uint(bmaxw) << 32) |
                                 (unsigned long long)(8192u - miw);
        __syncthreads();  // the ONLY barrier per iteration (parity-double-buffered slots)
        ulonglong2 kp0 = *(const ulonglong2*)&sm.f.sKey[par][0];  // 2 x ds_read_b128
        ulonglong2 kp1 = *(const ulonglong2*)&sm.f.sKey[par][2];
        unsigned long long kk = u64max(u64max(kp0.x, kp0.y), u64max(kp1.x, kp1.y));
        int far = 8192 - (int)(unsigned)(kk & 0xffffffffull);
        cx = sm.f.ptsx[far];  // uniform LDS broadcast
        cy = sm.f.ptsy[far];
        cz = sm.f.ptsz[far];
    }
    __syncthreads();
    float* ob = newxyz + (size_t)b * 3072;
#pragma unroll
    for (int i = 0; i < 12; ++i) ob[t + 256 * i] = sm.f.cbuf[t + 256 * i];
}

// ---------------- merged ball query: blocks 0..2047 br0 (K=32), 2048..4095 br1 --
__global__ void ball_query2(const float* __restrict__ xyz, const float* __restrict__ newxyz,
                            int* __restrict__ idx0, int* __restrict__ idx1) {
    int bid = blockIdx.x;
    int br = (bid >= 2048);
    int K = br ? 64 : 32;
    float r2 = br ? (0.8f * 0.8f) : (0.4f * 0.4f);
    int* idxout = br ? idx1 : idx0;
    int wid = (((bid & 2047) * 256) + threadIdx.x) >> 6;  // query id, 0..8191
    int lane = threadIdx.x & 63;
    int b = wid >> 10;
    const float* q = newxyz + (size_t)wid * 3;
    float qx = q[0], qy = q[1], qz = q[2];
    const float* xb = xyz + (size_t)b * 8192 * 3;
    int* out = idxout + (size_t)wid * K;
    int count = 0;
    int first = 0;
    for (int base = 0; base < 8192 && count < K; base += 64) {
        int j = base + lane;
        float dx = __fsub_rn(xb[j * 3 + 0], qx);
        float dy = __fsub_rn(xb[j * 3 + 1], qy);
        float dz = __fsub_rn(xb[j * 3 + 2], qz);
        float d2 = __fadd_rn(__fadd_rn(__fmul_rn(dx, dx), __fmul_rn(dy, dy)), __fmul_rn(dz, dz));
        bool in = d2 < r2;
        unsigned long long m = __ballot(in);
        if (count == 0 && m) first = base + __ffsll((long long)m) - 1;
        if (in) {
            int pos = count + __popcll(m & ((1ull << lane) - 1ull));
            if (pos < K) out[pos] = j;
        }
        count += __popcll(m);
    }
    if (count < K) {
        int fillv = (count > 0) ? first : 0;
        for (int p = count + lane; p < K; p += 64) out[p] = fillv;
    }
}

// ---------------- MFMA GEMM body (device fn; shared by solo + merged kernels) ---
// Fragment-major conflict-free LDS staging (R8-proven). smemRaw must be 16B-aligned,
// sized NCHUNK*16 + NT*64*4 bytes.
template <int Mp, int Kp, int IN_MODE, int OUT_MODE, int KSH, int NT>
__device__ __forceinline__ void gemm_body(
    int bid, char* smemRaw,
    const unsigned short* __restrict__ Wb, const unsigned short* __restrict__ Xin,
    const float* __restrict__ aff, const int* __restrict__ idx,
    const unsigned short* __restrict__ ftp, const float* __restrict__ newxyz,
    unsigned short* __restrict__ Yout, float* __restrict__ MX, float* __restrict__ MN,
    float* __restrict__ statS, float* __restrict__ statQ) {
    constexpr int MT = Mp / 64;
    constexpr int KS = Kp / 32;
    constexpr int NC = NT * 16;              // cols per block
    constexpr int NCHUNK = NT * KS * 64;     // 16B chunks in Bs
    unsigned short* Bs = (unsigned short*)smemRaw;
    float* sAux = (float*)(smemRaw + (size_t)NCHUNK * 16);
    int* sAuxI = (int*)sAux;

    const int tid = threadIdx.x;
    const int w = tid >> 6;
    const int lane = tid & 63;
    const int n = lane & 15;
    const int quad = lane >> 4;
    const int rbase = w * (Mp / 4);
    const long col0 = (long)bid * NC;

    short8 a[MT][KS];
#pragma unroll
    for (int mt = 0; mt < MT; ++mt)
#pragma unroll
        for (int ks = 0; ks < KS; ++ks)
            a[mt][ks] = *(const short8*)(Wb + (size_t)(rbase + mt * 16 + n) * Kp + ks * 32 + quad * 8);

    if constexpr (IN_MODE == 0) {
        for (int c = tid; c < NC; c += 256) {
            long colg = col0 + c;
            sAuxI[c] = idx[colg];
            long sk = colg >> KSH;
            sAux[NC + c] = newxyz[sk * 3 + 0];
            sAux[2 * NC + c] = newxyz[sk * 3 + 1];
            sAux[3 * NC + c] = newxyz[sk * 3 + 2];
        }
    } else {
        if (tid < 2 * Kp) sAux[tid] = aff[tid];
    }
    __syncthreads();

    // ---- Phase 1: build B-tile in LDS, chunk p = i*256+tid (lane-sequential) ----
#pragma unroll
    for (int i = 0; i < NCHUNK / 256; ++i) {
        int p = i * 256 + tid;
        int pl = p & 63;
        int pn = pl & 15;
        int pq = pl >> 4;
        int rest = p >> 6;  // pnt*KS + pks
        int pks = rest % KS;
        int pnt = rest / KS;
        int col = pnt * 16 + pn;
        int kc = pks * 4 + pq;  // 16B chunk index along K
        short8 v;
        if constexpr (IN_MODE == 0) {
            const int bb = (int)(col0 >> (KSH + 10));
            int j = sAuxI[col];
            v = *(const short8*)(ftp + ((long)(bb * 8192 + j)) * 96 + kc * 8);
            if (kc == 0) {  // rel-xyz patch: channels 0..2
                v[0] = (short)f2bf(bf2f((unsigned short)v[0]) - sAux[NC + col]);
                v[1] = (short)f2bf(bf2f((unsigned short)v[1]) - sAux[2 * NC + col]);
                v[2] = (short)f2bf(bf2f((unsigned short)v[2]) - sAux[3 * NC + col]);
            }
        } else {
            short8 raw = *(const short8*)(Xin + (col0 + col) * (long)Kp + kc * 8);
#pragma unroll
            for (int e = 0; e < 8; ++e) {
                float xf = bf2f((unsigned short)raw[e]);
                xf = fmaxf(fmaf(xf, sAux[kc * 8 + e], sAux[Kp + kc * 8 + e]), 0.f);
                v[e] = (short)f2bf(xf);
            }
        }
        *(short8*)(&Bs[p * 8]) = v;
    }
    __syncthreads();

    // ---- Phase 2: MFMA from LDS fragments (lane-sequential ds_read_b128) ----
    f32x4 acc[MT][NT];
#pragma unroll
    for (int mt = 0; mt < MT; ++mt)
#pragma unroll
        for (int nt = 0; nt < NT; ++nt)
#pragma unroll
            for (int r = 0; r < 4; ++r) acc[mt][nt][r] = 0.f;

#pragma unroll
    for (int ks = 0; ks < KS; ++ks) {
#pragma unroll
        for (int nt = 0; nt < NT; ++nt) {
            short8 bfr = *(const short8*)(&Bs[((nt * KS + ks) * 64 + lane) * 8]);
#pragma unroll
            for (int mt = 0; mt < MT; ++mt)
                acc[mt][nt] = __builtin_amdgcn_mfma_f32_16x16x32_bf16(a[mt][ks], bfr, acc[mt][nt], 0, 0, 0);
        }
    }

    // ---- stats: per-channel sum / sumsq ----
    const int slot = bid & 127;
#pragma unroll
    for (int mt = 0; mt < MT; ++mt)
#pragma unroll
        for (int r = 0; r < 4; ++r) {
            float s = 0.f, q = 0.f;
#pragma unroll
            for (int nt = 0; nt < NT; ++nt) {
                float v = acc[mt][nt][r];
                s += v;
                q = fmaf(v, v, q);
            }
#pragma unroll
            for (int off = 1; off < 16; off <<= 1) {
                s += __shfl_xor(s, off, 16);
                q += __shfl_xor(q, off, 16);
            }
            if (n == 0) {
                int ch = rbase + mt * 16 + quad * 4 + r;
                atomicAdd(statS + (size_t)ch * 128 + slot, s);
                atomicAdd(statQ + (size_t)ch * 128 + slot, q);
            }
        }

    if constexpr (OUT_MODE == 0) {
#pragma unroll
        for (int mt = 0; mt < MT; ++mt)
#pragma unroll
            for (int nt = 0; nt < NT; ++nt) {
                long col = col0 + nt * 16 + n;
                unsigned p0 = f2bf(acc[mt][nt][0]) | ((unsigned)f2bf(acc[mt][nt][1]) << 16);
                unsigned p1 = f2bf(acc[mt][nt][2]) | ((unsigned)f2bf(acc[mt][nt][3]) << 16);
                uint2 st; st.x = p0; st.y = p1;
                *(uint2*)(Yout + col * Mp + rbase + mt * 16 + quad * 4) = st;
            }
    } else {
        constexpr int GRP = (1 << KSH) / 16;  // n-tiles per K-sample group (2 or 4)
        constexpr int NG = NT / GRP;          // groups per block
#pragma unroll
        for (int mt = 0; mt < MT; ++mt)
#pragma unroll
            for (int r = 0; r < 4; ++r) {
#pragma unroll
                for (int gh = 0; gh < NG; ++gh) {
                    float mx = acc[mt][GRP * gh][r], mn = acc[mt][GRP * gh][r];
#pragma unroll
                    for (int e = 1; e < GRP; ++e) {
                        mx = fmaxf(mx, acc[mt][GRP * gh + e][r]);
                        mn = fminf(mn, acc[mt][GRP * gh + e][r]);
                    }
#pragma unroll
                    for (int off = 1; off < 16; off <<= 1) {
                        mx = fmaxf(mx, __shfl_xor(mx, off, 16));
                        mn = fminf(mn, __shfl_xor(mn, off, 16));
                    }
                    if (n == 0) {
                        int ch = rbase + mt * 16 + quad * 4 + r;
                        long g = (col0 >> KSH) + gh;
                        MX[(long)ch * 8192 + g] = mx;
                        MN[(long)ch * 8192 + g] = mn;
                    }
                }
            }
    }
}

// ---------------- solo gemm kernel wrapper --------------------------------------
template <int Mp, int Kp, int IN_MODE, int OUT_MODE, int KSH, int NT>
__global__ __launch_bounds__(256) void gemm_mfma(
    const unsigned short* __restrict__ Wb, const unsigned short* __restrict__ Xin,
    const float* __restrict__ aff, const int* __restrict__ idx,
    const unsigned short* __restrict__ ftp, const float* __restrict__ newxyz,
    unsigned short* __restrict__ Yout, float* __restrict__ MX, float* __restrict__ MN,
    float* __restrict__ statS, float* __restrict__ statQ) {
    constexpr int SMEM = NT * (Kp / 32) * 64 * 16 + NT * 64 * 4;
    __shared__ alignas(16) char smem[SMEM];
    gemm_body<Mp, Kp, IN_MODE, OUT_MODE, KSH, NT>(blockIdx.x, smem, Wb, Xin, aff, idx, ftp,
                                                  newxyz, Yout, MX, MN, statS, statQ);
}

// ---------------- merged: L2-br0 (blocks < nA) | L0-br1 (blocks >= nA) ----------
__global__ __launch_bounds__(256) void gemm_l2b0_l0b1(
    const unsigned short* __restrict__ WbA, const unsigned short* __restrict__ XinA,
    const float* __restrict__ affA, float* __restrict__ MXA, float* __restrict__ MNA,
    float* __restrict__ sSA, float* __restrict__ sQA,
    const unsigned short* __restrict__ WbB, const int* __restrict__ idxB,
    const unsigned short* __restrict__ ftpB, const float* __restrict__ newxyzB,
    unsigned short* __restrict__ YoutB, float* __restrict__ sSB, float* __restrict__ sQB,
    int nA) {
    extern __shared__ char smem[];
    if ((int)blockIdx.x < nA)
        gemm_body<128, 64, 1, 1, 5, 8>((int)blockIdx.x, smem, WbA, XinA, affA, nullptr, nullptr,
                                       nullptr, nullptr, MXA, MNA, sSA, sQA);
    else
        gemm_body<64, 96, 0, 0, 6, 16>((int)blockIdx.x - nA, smem, WbB, nullptr, nullptr, idxB,
                                       ftpB, newxyzB, YoutB, nullptr, nullptr, sSB, sQB);
}

// ---------------- merged: L1-br1 (blocks < nA) | final_out-br0 (blocks >= nA) ---
__global__ __launch_bounds__(256) void gemm_l1b1_fo0(
    const unsigned short* __restrict__ Wb, const unsigned short* __restrict__ Xin,
    const float* __restrict__ aff, unsigned short* __restrict__ Yout,
    float* __restrict__ sS, float* __restrict__ sQ,
    const float* __restrict__ MX, const float* __restrict__ MN,
    const float* __restrict__ affF, float* __restrict__ out1, int nA) {
    extern __shared__ char smem[];
    if ((int)blockIdx.x < nA) {
        gemm_body<128, 64, 1, 0, 6, 8>((int)blockIdx.x, smem, Wb, Xin, aff, nullptr, nullptr,
                                       nullptr, Yout, nullptr, nullptr, sS, sQ);
    } else {
        long i = (long)((int)blockIdx.x - nA) * 256 + threadIdx.x;  // over 128*8192
        int c = (int)(i >> 13);
        int gidx = (int)(i & 8191);
        int b = gidx >> 10, s = gidx & 1023;
        float sc = affF[c], sh = affF[128 + c];
        float v = fmaxf(fmaxf(sc * MX[i] + sh, sc * MN[i] + sh), 0.f);
        out1[((long)b * 384 + c) * 1024 + s] = v;
    }
}

// ---------------- finalize BN constants -----------------------------------------
__global__ void finalize_kernel(const float* __restrict__ sS, const float* __restrict__ sQ,
                                const float* __restrict__ g, const float* __restrict__ b,
                                float* __restrict__ aff, int C, float invCount) {
    int c = threadIdx.x + blockIdx.x * blockDim.x;
    if (c >= C) return;
    float s = 0.f, q = 0.f;
    for (int k = 0; k < 128; ++k) { s += sS[c * 128 + k]; q += sQ[c * 128 + k]; }
    float mean = s * invCount;
    float var = fmaxf(q * invCount - mean * mean, 0.f);
    float sc = g[c] / sqrtf(var + 1e-5f);
    float sh = b[c] - mean * sc;
    aff[c] = sc;
    aff[C + c] = sh;
}

// two-layer finalize in one launch (block 0 -> set0, block 1 -> set1)
__global__ void finalize2_kernel(const float* __restrict__ sS0, const float* __restrict__ sQ0,
                                 const float* __restrict__ g0, const float* __restrict__ b0,
                                 float* __restrict__ aff0, int C0, float ic0,
                                 const float* __restrict__ sS1, const float* __restrict__ sQ1,
                                 const float* __restrict__ g1, const float* __restrict__ b1,
                                 float* __restrict__ aff1, int C1, float ic1) {
    const float* sS = blockIdx.x ? sS1 : sS0;
    const float* sQ = blockIdx.x ? sQ1 : sQ0;
    const float* g = blockIdx.x ? g1 : g0;
    const float* b = blockIdx.x ? b1 : b0;
    float* aff = blockIdx.x ? aff1 : aff0;
    int C = blockIdx.x ? C1 : C0;
    float ic = blockIdx.x ? ic1 : ic0;
    int c = threadIdx.x;
    if (c >= C) return;
    float s = 0.f, q = 0.f;
    for (int k = 0; k < 128; ++k) { s += sS[c * 128 + k]; q += sQ[c * 128 + k]; }
    float mean = s * ic;
    float var = fmaxf(q * ic - mean * mean, 0.f);
    float sc = g[c] / sqrtf(var + 1e-5f);
    float sh = b[c] - mean * sc;
    aff[c] = sc;
    aff[C + c] = sh;
}

// ---------------- final output (br1) --------------------------------------------
__global__ void final_out_kernel(const float* __restrict__ MX, const float* __restrict__ MN,
                                 const float* __restrict__ aff, float* __restrict__ out1,
                                 int Cout, int cOff) {
    long i = (long)blockIdx.x * 256 + threadIdx.x;
    int c = (int)(i >> 13);
    int gidx = (int)(i & 8191);
    int b = gidx >> 10, s = gidx & 1023;
    float sc = aff[c], sh = aff[Cout + c];
    float v = fmaxf(fmaxf(sc * MX[i] + sh, sc * MN[i] + sh), 0.f);
    out1[((long)b * 384 + cOff + c) * 1024 + s] = v;
}

// ---------------- host ----------------------------------------------------------
extern "C" void kernel_launch(void* const* d_in, const int* in_sizes, int n_in,
                              void* d_out, int out_size, void* d_ws, size_t ws_size,
                              hipStream_t stream) {
    const float* xyz = (const float*)d_in[0];
    const float* feat = (const float*)d_in[1];
    const float *W[6], *G[6], *Bi[6];
    for (int l = 0; l < 6; ++l) {
        W[l] = (const float*)d_in[2 + l * 3];
        G[l] = (const float*)d_in[3 + l * 3];
        Bi[l] = (const float*)d_in[4 + l * 3];
    }
    char* ws = (char*)d_ws;
    float* out0 = (float*)d_out;
    float* out1 = (float*)d_out + 24576;

    unsigned short* wb = (unsigned short*)(ws + OFF_WBF);
    float* stats = (float*)(ws + OFF_STATS);
    float* affine = (float*)(ws + OFF_AFF);
    int* idx0 = (int*)(ws + OFF_IDX0);
    int* idx1 = (int*)(ws + OFF_IDX1);
    float* mx = (float*)(ws + OFF_MX);
    float* mn = (float*)(ws + OFF_MN);
    unsigned short* y0 = (unsigned short*)(ws + OFF_Y0);
    unsigned short* y1 = (unsigned short*)(ws + OFF_Y1);
    unsigned short* ftp = (unsigned short*)(ws + OFF_FEATT);

    hipMemsetAsync(stats, 0, STATS_BYTES, stream);
    fused_pre<<<1288, 256, 0, stream>>>(xyz, feat, out0, ftp, W[0], W[1], W[2], W[3], W[4],
                                        W[5], wb);
    ball_query2<<<4096, 256, 0, stream>>>(xyz, out0, idx0, idx1);

    const int wOff[6] = {0, 6144, 10240, 18432, 24576, 32768};
    int stOff[6], afOff[6];
    {
        const int Cs[6] = {64, 64, 128, 64, 128, 256};
        int so = 0, ao = 0;
        for (int l = 0; l < 6; ++l) {
            stOff[l] = so; so += Cs[l] * 256;
            afOff[l] = ao; ao += Cs[l] * 2;
        }
    }
    const float ic0 = 1.f / (float)(8L * 1024 * 32);  // br0 NCOL
    const float ic1 = 1.f / (float)(8L * 1024 * 64);  // br1 NCOL

    // ---- br0 L0, L1 ----
    gemm_mfma<64, 96, 0, 0, 5, 16><<<1024, 256, 0, stream>>>(
        wb + wOff[0], nullptr, nullptr, idx0, ftp, out0, y0, nullptr, nullptr,
        stats + stOff[0], stats + stOff[0] + 64 * 128);
    finalize_kernel<<<1, 256, 0, stream>>>(stats + stOff[0], stats + stOff[0] + 64 * 128,
                                           G[0], Bi[0], affine + afOff[0], 64, ic0);
    gemm_mfma<64, 64, 1, 0, 5, 16><<<1024, 256, 0, stream>>>(
        wb + wOff[1], y0, affine + afOff[0], nullptr, nullptr, nullptr, y1, nullptr,
        nullptr, stats + stOff[1], stats + stOff[1] + 64 * 128);
    finalize_kernel<<<1, 256, 0, stream>>>(stats + stOff[1], stats + stOff[1] + 64 * 128,
                                           G[1], Bi[1], affine + afOff[1], 64, ic0);

    // ---- merged: L2-br0 (2048 blocks) | L0-br1 (2048 blocks) ----
    gemm_l2b0_l0b1<<<4096, 256, 53248, stream>>>(
        wb + wOff[2], y1, affine + afOff[1], mx, mn, stats + stOff[2],
        stats + stOff[2] + 128 * 128, wb + wOff[3], idx1, ftp, out0, y0, stats + stOff[3],
        stats + stOff[3] + 64 * 128, 2048);
    finalize2_kernel<<<2, 256, 0, stream>>>(
        stats + stOff[2], stats + stOff[2] + 128 * 128, G[2], Bi[2], affine + afOff[2], 128, ic0,
        stats + stOff[3], stats + stOff[3] + 64 * 128, G[3], Bi[3], affine + afOff[3], 64, ic1);

    // ---- merged: L1-br1 (4096 blocks) | final_out-br0 (4096 blocks) ----
    gemm_l1b1_fo0<<<8192, 256, 18432, stream>>>(
        wb + wOff[4], y0, affine + afOff[3], y1, stats + stOff[4], stats + stOff[4] + 128 * 128,
        mx, mn, affine + afOff[2], out1, 4096);
    finalize_kernel<<<1, 256, 0, stream>>>(stats + stOff[4], stats + stOff[4] + 128 * 128,
                                           G[4], Bi[4], affine + afOff[4], 128, ic1);

    // ---- br1 L2 + finalize + final_out ----
    gemm_mfma<256, 128, 1, 1, 6, 4><<<8192, 256, 0, stream>>>(
        wb + wOff[5], y1, affine + afOff[4], nullptr, nullptr, nullptr, nullptr, mx, mn,
        stats + stOff[5], stats + stOff[5] + 256 * 128);
    finalize_kernel<<<1, 256, 0, stream>>>(stats + stOff[5], stats + stOff[5] + 256 * 128,
                                           G[5], Bi[5], affine + afOff[5], 256, ic1);
    final_out_kernel<<<(256 * 8192) / 256, 256, 0, stream>>>(mx, mn, affine + afOff[5], out1,
                                                             256, 128);
}

// Round 14
// 1523.157 us; speedup vs baseline: 1.1486x; 1.0458x over previous
//
#include <hip/hip_runtime.h>
#include <hip/hip_bf16.h>
#include <cstdint>

// B=8, N=8192, S=1024, C=64
// branch0: r=0.4, K=32, layers 64x67, 64x64, 128x64
// branch1: r=0.8, K=64, layers 64x67, 128x64, 256x128

typedef __attribute__((ext_vector_type(8))) short short8;
typedef __attribute__((ext_vector_type(4))) float f32x4;
typedef __attribute__((ext_vector_type(2))) float f32x2;

__device__ __forceinline__ float bf2f(unsigned short u) {
    return __uint_as_float(((unsigned)u) << 16);
}
__device__ __forceinline__ unsigned short f2bf(float f) {
    unsigned u = __float_as_uint(f);
    return (unsigned short)((u + 0x7fffu + ((u >> 16) & 1u)) >> 16);  // RNE
}

// Wave-64 reductions on the VALU pipe via DPP (rocPRIM pattern): result in lane 63.
__device__ __forceinline__ float wave_red_max_f32(float v) {
#define DPPSTEP(ctrl)                                                                  \
    {                                                                                  \
        int _t = __builtin_amdgcn_update_dpp((int)0xFF800000, __float_as_int(v), ctrl, \
                                             0xf, 0xf, false);                         \
        v = fmaxf(v, __int_as_float(_t));                                              \
    }
    DPPSTEP(0x111) DPPSTEP(0x112) DPPSTEP(0x114) DPPSTEP(0x118) DPPSTEP(0x142) DPPSTEP(0x143)
#undef DPPSTEP
    return v;
}
__device__ __forceinline__ unsigned wave_red_min_u32(unsigned v) {
#define DPPSTEP(ctrl)                                                                   \
    {                                                                                   \
        unsigned _t = (unsigned)__builtin_amdgcn_update_dpp((int)0xFFFFFFFF, (int)v,    \
                                                            ctrl, 0xf, 0xf, false);     \
        v = v < _t ? v : _t;                                                            \
    }
    DPPSTEP(0x111) DPPSTEP(0x112) DPPSTEP(0x114) DPPSTEP(0x118) DPPSTEP(0x142) DPPSTEP(0x143)
#undef DPPSTEP
    return v;
}
__device__ __forceinline__ unsigned long long u64max(unsigned long long a, unsigned long long b) {
    return a > b ? a : b;
}
__device__ __forceinline__ unsigned u32min(unsigned a, unsigned b) { return a < b ? a : b; }

// ---------------- workspace layout (bytes); peak = 224,395,264 ------------------
static const size_t OFF_WBF   = 0;          // packed bf16 weights, 65536 elems (128 KB)
static const size_t OFF_STATS = 262144;     // 704 ch * 128 slots * 2 * 4B
static const size_t STATS_BYTES = 720896;
static const size_t OFF_AFF   = 1048576;    // per-layer scale/shift
static const size_t OFF_IDX0  = 2097152;    // 8*1024*32 ints
static const size_t OFF_IDX1  = 3145728;    // 8*1024*64 ints
static const size_t OFF_MX    = 5242880;    // 256*8192 fp32
static const size_t OFF_MN    = 13631488;
static const size_t OFF_Y0    = 22020096;   // bf16 X^T [NCOL][64]  (max 67 MB)
static const size_t OFF_Y1    = 90177536;   // bf16 X^T [NCOL][128] (max 134 MB)
static const size_t OFF_FEATT = 211812352;  // bf16 [8*8192][96] = 12.58 MB, overlaps Y1 tail
// (featTp last read in br1-L0; Y1 beyond 121.6 MB only written by br1-L1, which runs later)

// ---------------- fused pre-kernel (256 threads/block):
// FPS (blocks 0..7) + feat transpose (8..1031) + weight pack (1032..1287) ----
__global__ __launch_bounds__(256) void fused_pre(
    const float* __restrict__ xyz, const float* __restrict__ feat,
    float* __restrict__ newxyz, unsigned short* __restrict__ ft,
    const float* __restrict__ w0, const float* __restrict__ w1, const float* __restrict__ w2,
    const float* __restrict__ w3, const float* __restrict__ w4, const float* __restrict__ w5,
    unsigned short* __restrict__ wb) {
    __shared__ union alignas(16) SM {
        struct {
            float ptsx[8200], ptsy[8200], ptsz[8200];
            float ldsM[16][3];
            float meanv[3];
            alignas(16) unsigned long long sKey[2][4];
            float cbuf[3072];
        } f;
        float tile[64][65];
    } sm;
    const int tid = threadIdx.x;

    if (blockIdx.x >= 1032) {
        int id = (int)(blockIdx.x - 1032) * 256 + tid;  // 0..65535
        const int psz[6] = {6144, 4096, 8192, 6144, 8192, 32768};
        const int Kp[6] = {96, 64, 64, 96, 64, 128};
        const int Ks[6] = {67, 64, 64, 67, 64, 128};
        const float* wp[6] = {w0, w1, w2, w3, w4, w5};
        int off = 0;
        for (int l = 0; l < 6; ++l) {
            if (id < off + psz[l]) {
                int e = id - off;
                int m = e / Kp[l], k = e - m * Kp[l];
                float v = (k < Ks[l]) ? wp[l][m * Ks[l] + k] : 0.f;
                wb[id] = f2bf(v);
                return;
            }
            off += psz[l];
        }
        return;
    }

    if (blockIdx.x >= 8) {
        int tb = (int)blockIdx.x - 8;  // 0..1023
        int b = tb >> 7;
        int j0 = (tb & 127) * 64;
#pragma unroll
        for (int i = 0; i < 16; ++i) {
            int e = i * 256 + tid;
            int c = e >> 6, j = e & 63;
            sm.tile[j][c] = feat[((size_t)b * 64 + c) * 8192 + j0 + j];
        }
        __syncthreads();
#pragma unroll
        for (int i = 0; i < 16; ++i) {
            int e = i * 256 + tid;
            int j = e >> 6, c = e & 63;
            ft[((size_t)(b * 8192 + j0 + j)) * 96 + 3 + c] = f2bf(sm.tile[j][c]);
        }
        if (tid < 64) {
            int j = tid;
            size_t base = ((size_t)(b * 8192 + j0 + j)) * 96;
            const float* xp = xyz + ((size_t)b * 8192 + j0 + j) * 3;
            ft[base + 0] = f2bf(xp[0]);
            ft[base + 1] = f2bf(xp[1]);
            ft[base + 2] = f2bf(xp[2]);
        } else if (tid < 128) {
            int j = tid - 64;
            size_t base = ((size_t)(b * 8192 + j0 + j)) * 96;
            for (int c = 67; c < 96; ++c) ft[base + c] = 0;
        }
        return;
    }

    // ---- FPS: 4 waves (1/SIMD), 32 pts/thread, in-loop running argmax (R13) ----
    const int b = blockIdx.x;
    const int t = tid;
    const int lane = t & 63, wv = t >> 6;
    const float* xb = xyz + (size_t)b * 8192 * 3;

    f32x2 px[16], py[16], pz[16], d[16];
#pragma unroll
    for (int k = 0; k < 16; ++k) {
        int q0 = t + 256 * (2 * k);
        int q1 = t + 256 * (2 * k + 1);
        px[k].x = xb[q0 * 3 + 0]; px[k].y = xb[q1 * 3 + 0];
        py[k].x = xb[q0 * 3 + 1]; py[k].y = xb[q1 * 3 + 1];
        pz[k].x = xb[q0 * 3 + 2]; pz[k].y = xb[q1 * 3 + 2];
        d[k].x = 1e10f; d[k].y = 1e10f;
        sm.f.ptsx[q0 + 1] = px[k].x; sm.f.ptsx[q1 + 1] = px[k].y;
        sm.f.ptsy[q0 + 1] = py[k].x; sm.f.ptsy[q1 + 1] = py[k].y;
        sm.f.ptsz[q0 + 1] = pz[k].x; sm.f.ptsz[q1 + 1] = pz[k].y;
    }
    {
        float sx[4], sy[4], sz[4];
#pragma unroll
        for (int m = 0; m < 4; ++m) {
            int u = (t + 256 * m + 1023) & 1023;
            float ax = 0.f, ay = 0.f, az = 0.f;
#pragma unroll
            for (int jj = 0; jj < 8; ++jj) {
                int ia = u + 1024 * jj;
                ax += xb[ia * 3 + 0]; ay += xb[ia * 3 + 1]; az += xb[ia * 3 + 2];
            }
            sx[m] = ax; sy[m] = ay; sz[m] = az;
        }
#pragma unroll
        for (int off = 32; off; off >>= 1) {
#pragma unroll
            for (int m = 0; m < 4; ++m) {
                sx[m] += __shfl_xor(sx[m], off, 64);
                sy[m] += __shfl_xor(sy[m], off, 64);
                sz[m] += __shfl_xor(sz[m], off, 64);
            }
        }
        if (lane == 0) {
#pragma unroll
            for (int m = 0; m < 4; ++m) {
                sm.f.ldsM[wv + 4 * m][0] = sx[m];
                sm.f.ldsM[wv + 4 * m][1] = sy[m];
                sm.f.ldsM[wv + 4 * m][2] = sz[m];
            }
        }
    }
    __syncthreads();
    if (t < 3) {
        float s = 0.f;
        for (int w = 0; w < 16; ++w) s += sm.f.ldsM[w][t];
        sm.f.meanv[t] = s * (1.f / 8192.f);
    }
    __syncthreads();
    float cx = sm.f.meanv[0], cy = sm.f.meanv[1], cz = sm.f.meanv[2];
    const float mmx = cx, mmy = cy, mmz = cz;
    float dm = 1e10f;
    if (t == 0) { sm.f.ptsx[0] = cx; sm.f.ptsy[0] = cy; sm.f.ptsz[0] = cz; }
    __syncthreads();

    for (int it = 0; it < 1024; ++it) {
        if (t == 0) {
            sm.f.cbuf[it * 3 + 0] = cx;
            sm.f.cbuf[it * 3 + 1] = cy;
            sm.f.cbuf[it * 3 + 2] = cz;
        }
        f32x2 c0, c1, c2;
        c0.x = cx; c0.y = cx; c1.x = cy; c1.y = cy; c2.x = cz; c2.y = cz;
        float bv = -1e30f;
        unsigned bi = 0u;
        {
#pragma clang fp contract(off)
#pragma unroll
            for (int k = 0; k < 16; ++k) {
                f32x2 dx = px[k] - c0;
                f32x2 dy = py[k] - c1;
                f32x2 dz = pz[k] - c2;
                f32x2 dd = (dx * dx + dy * dy) + dz * dz;
                f32x2 nd = __builtin_elementwise_min(d[k], dd);
                d[k] = nd;
                bool g0 = nd.x > bv;
                bv = fmaxf(bv, nd.x);
                bi = g0 ? (unsigned)(t + 256 * (2 * k) + 1) : bi;
                bool g1 = nd.y > bv;
                bv = fmaxf(bv, nd.y);
                bi = g1 ? (unsigned)(t + 256 * (2 * k + 1) + 1) : bi;
            }
        }
        if (t == 0) {
            float dx = __fsub_rn(mmx, cx);
            float dy = __fsub_rn(mmy, cy);
            float dz = __fsub_rn(mmz, cz);
            float dd = __fadd_rn(__fadd_rn(__fmul_rn(dx, dx), __fmul_rn(dy, dy)), __fmul_rn(dz, dz));
            dm = fminf(dm, dd);
            bv = fmaxf(bv, dm);
        }
        float wm = wave_red_max_f32(bv);
        float bmaxw = __int_as_float(__builtin_amdgcn_readlane(__float_as_int(wm), 63));
        unsigned mi = (bv == bmaxw) ? bi : 0xFFFFFFFFu;
        if (t == 0 && dm == bmaxw) mi = 0u;
        unsigned wmin = wave_red_min_u32(mi);
        unsigned miw = (unsigned)__builtin_amdgcn_readlane((int)wmin, 63);
        int par = it & 1;
        if (lane == 0)
            sm.f.sKey[par][wv] = ((unsigned long long)__float_as_uint(bmaxw) << 32) |
                                 (unsigned long long)(8192u - miw);
        __syncthreads();
        ulonglong2 kp0 = *(const ulonglong2*)&sm.f.sKey[par][0];
        ulonglong2 kp1 = *(const ulonglong2*)&sm.f.sKey[par][2];
        unsigned long long kk = u64max(u64max(kp0.x, kp0.y), u64max(kp1.x, kp1.y));
        int far = 8192 - (int)(unsigned)(kk & 0xffffffffull);
        cx = sm.f.ptsx[far];
        cy = sm.f.ptsy[far];
        cz = sm.f.ptsz[far];
    }
    __syncthreads();
    float* ob = newxyz + (size_t)b * 3072;
#pragma unroll
    for (int i = 0; i < 12; ++i) ob[t + 256 * i] = sm.f.cbuf[t + 256 * i];
}

// ---------------- merged ball query: blocks 0..2047 br0 (K=32), 2048..4095 br1 --
__global__ void ball_query2(const float* __restrict__ xyz, const float* __restrict__ newxyz,
                            int* __restrict__ idx0, int* __restrict__ idx1) {
    int bid = blockIdx.x;
    int br = (bid >= 2048);
    int K = br ? 64 : 32;
    float r2 = br ? (0.8f * 0.8f) : (0.4f * 0.4f);
    int* idxout = br ? idx1 : idx0;
    int wid = (((bid & 2047) * 256) + threadIdx.x) >> 6;
    int lane = threadIdx.x & 63;
    int b = wid >> 10;
    const float* q = newxyz + (size_t)wid * 3;
    float qx = q[0], qy = q[1], qz = q[2];
    const float* xb = xyz + (size_t)b * 8192 * 3;
    int* out = idxout + (size_t)wid * K;
    int count = 0;
    int first = 0;
    for (int base = 0; base < 8192 && count < K; base += 64) {
        int j = base + lane;
        float dx = __fsub_rn(xb[j * 3 + 0], qx);
        float dy = __fsub_rn(xb[j * 3 + 1], qy);
        float dz = __fsub_rn(xb[j * 3 + 2], qz);
        float d2 = __fadd_rn(__fadd_rn(__fmul_rn(dx, dx), __fmul_rn(dy, dy)), __fmul_rn(dz, dz));
        bool in = d2 < r2;
        unsigned long long m = __ballot(in);
        if (count == 0 && m) first = base + __ffsll((long long)m) - 1;
        if (in) {
            int pos = count + __popcll(m & ((1ull << lane) - 1ull));
            if (pos < K) out[pos] = j;
        }
        count += __popcll(m);
    }
    if (count < K) {
        int fillv = (count > 0) ? first : 0;
        for (int p = count + lane; p < K; p += 64) out[p] = fillv;
    }
}

// ---------------- single-tile MFMA GEMM (IN_MODE 0 gather layers) ---------------
// Fragment-major conflict-free LDS staging (R8-proven).
template <int Mp, int Kp, int KSH, int NT>
__global__ __launch_bounds__(256) void gemm_gather(
    const unsigned short* __restrict__ Wb, const int* __restrict__ idx,
    const unsigned short* __restrict__ ftp, const float* __restrict__ newxyz,
    unsigned short* __restrict__ Yout, float* __restrict__ statS, float* __restrict__ statQ) {
    constexpr int MT = Mp / 64;
    constexpr int KS = Kp / 32;
    constexpr int NC = NT * 16;
    constexpr int NCHUNK = NT * KS * 64;
    __shared__ unsigned short Bs[NCHUNK * 8];
    __shared__ float sAux[NT * 64];
    int* sAuxI = (int*)sAux;

    const int tid = threadIdx.x;
    const int w = tid >> 6;
    const int lane = tid & 63;
    const int n = lane & 15;
    const int quad = lane >> 4;
    const int rbase = w * (Mp / 4);
    const long col0 = (long)blockIdx.x * NC;

    short8 a[MT][KS];
#pragma unroll
    for (int mt = 0; mt < MT; ++mt)
#pragma unroll
        for (int ks = 0; ks < KS; ++ks)
            a[mt][ks] = *(const short8*)(Wb + (size_t)(rbase + mt * 16 + n) * Kp + ks * 32 + quad * 8);

    for (int c = tid; c < NC; c += 256) {
        long colg = col0 + c;
        sAuxI[c] = idx[colg];
        long sk = colg >> KSH;
        sAux[NC + c] = newxyz[sk * 3 + 0];
        sAux[2 * NC + c] = newxyz[sk * 3 + 1];
        sAux[3 * NC + c] = newxyz[sk * 3 + 2];
    }
    __syncthreads();

#pragma unroll
    for (int i = 0; i < NCHUNK / 256; ++i) {
        int p = i * 256 + tid;
        int pl = p & 63;
        int pn = pl & 15;
        int pq = pl >> 4;
        int rest = p >> 6;
        int pks = rest % KS;
        int pnt = rest / KS;
        int col = pnt * 16 + pn;
        int kc = pks * 4 + pq;
        const int bb = (int)(col0 >> (KSH + 10));
        int j = sAuxI[col];
        short8 v = *(const short8*)(ftp + ((long)(bb * 8192 + j)) * 96 + kc * 8);
        if (kc == 0) {
            v[0] = (short)f2bf(bf2f((unsigned short)v[0]) - sAux[NC + col]);
            v[1] = (short)f2bf(bf2f((unsigned short)v[1]) - sAux[2 * NC + col]);
            v[2] = (short)f2bf(bf2f((unsigned short)v[2]) - sAux[3 * NC + col]);
        }
        *(short8*)(&Bs[p * 8]) = v;
    }
    __syncthreads();

    f32x4 acc[MT][NT];
#pragma unroll
    for (int mt = 0; mt < MT; ++mt)
#pragma unroll
        for (int nt = 0; nt < NT; ++nt)
#pragma unroll
            for (int r = 0; r < 4; ++r) acc[mt][nt][r] = 0.f;

#pragma unroll
    for (int ks = 0; ks < KS; ++ks) {
#pragma unroll
        for (int nt = 0; nt < NT; ++nt) {
            short8 bfr = *(const short8*)(&Bs[((nt * KS + ks) * 64 + lane) * 8]);
#pragma unroll
            for (int mt = 0; mt < MT; ++mt)
                acc[mt][nt] = __builtin_amdgcn_mfma_f32_16x16x32_bf16(a[mt][ks], bfr, acc[mt][nt], 0, 0, 0);
        }
    }

    const int slot = (int)(blockIdx.x & 127);
#pragma unroll
    for (int mt = 0; mt < MT; ++mt)
#pragma unroll
        for (int r = 0; r < 4; ++r) {
            float s = 0.f, q = 0.f;
#pragma unroll
            for (int nt = 0; nt < NT; ++nt) {
                float v = acc[mt][nt][r];
                s += v;
                q = fmaf(v, v, q);
            }
#pragma unroll
            for (int off = 1; off < 16; off <<= 1) {
                s += __shfl_xor(s, off, 16);
                q += __shfl_xor(q, off, 16);
            }
            if (n == 0) {
                int ch = rbase + mt * 16 + quad * 4 + r;
                atomicAdd(statS + (size_t)ch * 128 + slot, s);
                atomicAdd(statQ + (size_t)ch * 128 + slot, q);
            }
        }

#pragma unroll
    for (int mt = 0; mt < MT; ++mt)
#pragma unroll
        for (int nt = 0; nt < NT; ++nt) {
            long col = col0 + nt * 16 + n;
            unsigned p0 = f2bf(acc[mt][nt][0]) | ((unsigned)f2bf(acc[mt][nt][1]) << 16);
            unsigned p1 = f2bf(acc[mt][nt][2]) | ((unsigned)f2bf(acc[mt][nt][3]) << 16);
            uint2 st; st.x = p0; st.y = p1;
            *(uint2*)(Yout + col * Mp + rbase + mt * 16 + quad * 4) = st;
        }
}

// ---------------- persistent double-buffered MFMA GEMM (IN_MODE 1 layers) -------
// Each block processes ntiles/grid tiles; tile t+1's global loads are staged into
// the alternate LDS buffer while tile t's MFMA+epilogue runs -> global latency
// hidden inside the block (was serialized: stage -> barrier -> MFMA at 2-3
// blocks/CU). A-frags + affine loaded once per block; stats accumulate in
// registers across tiles, one atomic set per block (~10x fewer atomics).
#define STAGE_IN1(TILE, BUFI)                                                       \
    {                                                                               \
        long scol0 = (long)(TILE) * NC;                                             \
        short8 raw[CPT];                                                            \
        _Pragma("unroll") for (int i = 0; i < CPT; ++i)                             \
            raw[i] = *(const short8*)(Xin + (scol0 + colC[i]) * (long)Kp + kcC[i] * 8); \
        _Pragma("unroll") for (int i = 0; i < CPT; ++i) {                           \
            short8 v;                                                               \
            _Pragma("unroll") for (int e = 0; e < 8; ++e) {                         \
                float xf = bf2f((unsigned short)raw[i][e]);                         \
                xf = fmaxf(fmaf(xf, sAff[kcC[i] * 8 + e], sAff[Kp + kcC[i] * 8 + e]), 0.f); \
                v[e] = (short)f2bf(xf);                                             \
            }                                                                       \
            *(short8*)(&Bs[(BUFI)][(i * 256 + tid) * 8]) = v;                       \
        }                                                                           \
    }

template <int Mp, int Kp, int OUT_MODE, int KSH, int NT>
__global__ __launch_bounds__(256) void gemm_pers(
    const unsigned short* __restrict__ Wb, const unsigned short* __restrict__ Xin,
    const float* __restrict__ aff, unsigned short* __restrict__ Yout,
    float* __restrict__ MX, float* __restrict__ MN,
    float* __restrict__ statS, float* __restrict__ statQ, int ntiles) {
    constexpr int MT = Mp / 64;
    constexpr int KS = Kp / 32;
    constexpr int NC = NT * 16;
    constexpr int NCHUNK = NT * KS * 64;
    constexpr int CPT = NCHUNK / 256;
    __shared__ unsigned short Bs[2][NCHUNK * 8];
    __shared__ float sAff[2 * 128];  // up to Kp=128

    const int tid = threadIdx.x;
    const int w = tid >> 6;
    const int lane = tid & 63;
    const int n = lane & 15;
    const int quad = lane >> 4;
    const int rbase = w * (Mp / 4);

    // per-thread chunk->(col,kc) constants (fragment-major layout, R8-proven)
    int colC[CPT], kcC[CPT];
    {
        int pl = tid & 63;
        int pn = pl & 15;
        int pq = pl >> 4;
#pragma unroll
        for (int i = 0; i < CPT; ++i) {
            int rest = i * 4 + (tid >> 6);
            int pks = rest % KS;
            int pnt = rest / KS;
            colC[i] = pnt * 16 + pn;
            kcC[i] = pks * 4 + pq;
        }
    }

    short8 a[MT][KS];
#pragma unroll
    for (int mt = 0; mt < MT; ++mt)
#pragma unroll
        for (int ks = 0; ks < KS; ++ks)
            a[mt][ks] = *(const short8*)(Wb + (size_t)(rbase + mt * 16 + n) * Kp + ks * 32 + quad * 8);

    if (tid < 2 * Kp) sAff[tid] = aff[tid];
    float accS[MT][4], accQ[MT][4];
#pragma unroll
    for (int mt = 0; mt < MT; ++mt)
#pragma unroll
        for (int r = 0; r < 4; ++r) { accS[mt][r] = 0.f; accQ[mt][r] = 0.f; }
    __syncthreads();  // sAff ready

    if ((int)blockIdx.x < ntiles) STAGE_IN1((int)blockIdx.x, 0);
    __syncthreads();

    int g = 0;
    for (int t = (int)blockIdx.x; t < ntiles; t += (int)gridDim.x, ++g) {
        int tn = t + (int)gridDim.x;
        if (tn < ntiles) STAGE_IN1(tn, (g + 1) & 1);  // prefetch next tile

        const int cur = g & 1;
        const long col0 = (long)t * NC;
        f32x4 acc[MT][NT];
#pragma unroll
        for (int mt = 0; mt < MT; ++mt)
#pragma unroll
            for (int nt = 0; nt < NT; ++nt)
#pragma unroll
                for (int r = 0; r < 4; ++r) acc[mt][nt][r] = 0.f;

#pragma unroll
        for (int ks = 0; ks < KS; ++ks) {
#pragma unroll
            for (int nt = 0; nt < NT; ++nt) {
                short8 bfr = *(const short8*)(&Bs[cur][((nt * KS + ks) * 64 + lane) * 8]);
#pragma unroll
                for (int mt = 0; mt < MT; ++mt)
                    acc[mt][nt] =
                        __builtin_amdgcn_mfma_f32_16x16x32_bf16(a[mt][ks], bfr, acc[mt][nt], 0, 0, 0);
            }
        }

        // stats: accumulate per-lane across tiles (reduce + atomic once at end)
#pragma unroll
        for (int mt = 0; mt < MT; ++mt)
#pragma unroll
            for (int r = 0; r < 4; ++r) {
                float s = accS[mt][r], q = accQ[mt][r];
#pragma unroll
                for (int nt = 0; nt < NT; ++nt) {
                    float v = acc[mt][nt][r];
                    s += v;
                    q = fmaf(v, v, q);
                }
                accS[mt][r] = s;
                accQ[mt][r] = q;
            }

        if constexpr (OUT_MODE == 0) {
#pragma unroll
            for (int mt = 0; mt < MT; ++mt)
#pragma unroll
                for (int nt = 0; nt < NT; ++nt) {
                    long col = col0 + nt * 16 + n;
                    unsigned p0 = f2bf(acc[mt][nt][0]) | ((unsigned)f2bf(acc[mt][nt][1]) << 16);
                    unsigned p1 = f2bf(acc[mt][nt][2]) | ((unsigned)f2bf(acc[mt][nt][3]) << 16);
                    uint2 st; st.x = p0; st.y = p1;
                    *(uint2*)(Yout + col * Mp + rbase + mt * 16 + quad * 4) = st;
                }
        } else {
            constexpr int GRP = (1 << KSH) / 16;
            constexpr int NG = NT / GRP;
#pragma unroll
            for (int mt = 0; mt < MT; ++mt)
#pragma unroll
                for (int r = 0; r < 4; ++r) {
#pragma unroll
                    for (int gh = 0; gh < NG; ++gh) {
                        float mx = acc[mt][GRP * gh][r], mn = acc[mt][GRP * gh][r];
#pragma unroll
                        for (int e = 1; e < GRP; ++e) {
                            mx = fmaxf(mx, acc[mt][GRP * gh + e][r]);
                            mn = fminf(mn, acc[mt][GRP * gh + e][r]);
                        }
#pragma unroll
                        for (int off = 1; off < 16; off <<= 1) {
                            mx = fmaxf(mx, __shfl_xor(mx, off, 16));
                            mn = fminf(mn, __shfl_xor(mn, off, 16));
                        }
                        if (n == 0) {
                            int ch = rbase + mt * 16 + quad * 4 + r;
                            long gg = (col0 >> KSH) + gh;
                            MX[(long)ch * 8192 + gg] = mx;
                            MN[(long)ch * 8192 + gg] = mn;
                        }
                    }
                }
        }
        __syncthreads();  // buf[cur] free to re-stage; buf[next] fully written
    }

    // final stats reduction + single atomic set per block
    const int slot = (int)(blockIdx.x & 127);
#pragma unroll
    for (int mt = 0; mt < MT; ++mt)
#pragma unroll
        for (int r = 0; r < 4; ++r) {
            float s = accS[mt][r], q = accQ[mt][r];
#pragma unroll
            for (int off = 1; off < 16; off <<= 1) {
                s += __shfl_xor(s, off, 16);
                q += __shfl_xor(q, off, 16);
            }
            if (n == 0) {
                int ch = rbase + mt * 16 + quad * 4 + r;
                atomicAdd(statS + (size_t)ch * 128 + slot, s);
                atomicAdd(statQ + (size_t)ch * 128 + slot, q);
            }
        }
}

// ---------------- finalize BN constants -----------------------------------------
__global__ void finalize_kernel(const float* __restrict__ sS, const float* __restrict__ sQ,
                                const float* __restrict__ g, const float* __restrict__ b,
                                float* __restrict__ aff, int C, float invCount) {
    int c = threadIdx.x + blockIdx.x * blockDim.x;
    if (c >= C) return;
    float s = 0.f, q = 0.f;
    for (int k = 0; k < 128; ++k) { s += sS[c * 128 + k]; q += sQ[c * 128 + k]; }
    float mean = s * invCount;
    float var = fmaxf(q * invCount - mean * mean, 0.f);
    float sc = g[c] / sqrtf(var + 1e-5f);
    float sh = b[c] - mean * sc;
    aff[c] = sc;
    aff[C + c] = sh;
}

// ---------------- final output ---------------------------------------------------
__global__ void final_out_kernel(const float* __restrict__ MX, const float* __restrict__ MN,
                                 const float* __restrict__ aff, float* __restrict__ out1,
                                 int Cout, int cOff) {
    long i = (long)blockIdx.x * 256 + threadIdx.x;
    int c = (int)(i >> 13);
    int gidx = (int)(i & 8191);
    int b = gidx >> 10, s = gidx & 1023;
    float sc = aff[c], sh = aff[Cout + c];
    float v = fmaxf(fmaxf(sc * MX[i] + sh, sc * MN[i] + sh), 0.f);
    out1[((long)b * 384 + cOff + c) * 1024 + s] = v;
}

// ---------------- host -----------------------------------------------------------
extern "C" void kernel_launch(void* const* d_in, const int* in_sizes, int n_in,
                              void* d_out, int out_size, void* d_ws, size_t ws_size,
                              hipStream_t stream) {
    const float* xyz = (const float*)d_in[0];
    const float* feat = (const float*)d_in[1];
    const float *W[6], *G[6], *Bi[6];
    for (int l = 0; l < 6; ++l) {
        W[l] = (const float*)d_in[2 + l * 3];
        G[l] = (const float*)d_in[3 + l * 3];
        Bi[l] = (const float*)d_in[4 + l * 3];
    }
    char* ws = (char*)d_ws;
    float* out0 = (float*)d_out;
    float* out1 = (float*)d_out + 24576;

    unsigned short* wb = (unsigned short*)(ws + OFF_WBF);
    float* stats = (float*)(ws + OFF_STATS);
    float* affine = (float*)(ws + OFF_AFF);
    int* idx0 = (int*)(ws + OFF_IDX0);
    int* idx1 = (int*)(ws + OFF_IDX1);
    float* mx = (float*)(ws + OFF_MX);
    float* mn = (float*)(ws + OFF_MN);
    unsigned short* y0 = (unsigned short*)(ws + OFF_Y0);
    unsigned short* y1 = (unsigned short*)(ws + OFF_Y1);
    unsigned short* ftp = (unsigned short*)(ws + OFF_FEATT);

    hipMemsetAsync(stats, 0, STATS_BYTES, stream);
    fused_pre<<<1288, 256, 0, stream>>>(xyz, feat, out0, ftp, W[0], W[1], W[2], W[3], W[4],
                                        W[5], wb);
    ball_query2<<<4096, 256, 0, stream>>>(xyz, out0, idx0, idx1);

    const int wOff[6] = {0, 6144, 10240, 18432, 24576, 32768};
    int stOff[6], afOff[6];
    {
        const int Cs[6] = {64, 64, 128, 64, 128, 256};
        int so = 0, ao = 0;
        for (int l = 0; l < 6; ++l) {
            stOff[l] = so; so += Cs[l] * 256;
            afOff[l] = ao; ao += Cs[l] * 2;
        }
    }
    const float ic0 = 1.f / (float)(8L * 1024 * 32);
    const float ic1 = 1.f / (float)(8L * 1024 * 64);
    const int GRID = 768;  // 3 blocks/CU target for persistent gemms

    // ---- branch 0 ----
    gemm_gather<64, 96, 5, 16><<<1024, 256, 0, stream>>>(
        wb + wOff[0], idx0, ftp, out0, y0, stats + stOff[0], stats + stOff[0] + 64 * 128);
    finalize_kernel<<<1, 256, 0, stream>>>(stats + stOff[0], stats + stOff[0] + 64 * 128,
                                           G[0], Bi[0], affine + afOff[0], 64, ic0);
    gemm_pers<64, 64, 0, 5, 8><<<GRID, 256, 0, stream>>>(
        wb + wOff[1], y0, affine + afOff[0], y1, nullptr, nullptr, stats + stOff[1],
        stats + stOff[1] + 64 * 128, 2048);
    finalize_kernel<<<1, 256, 0, stream>>>(stats + stOff[1], stats + stOff[1] + 64 * 128,
                                           G[1], Bi[1], affine + afOff[1], 64, ic0);
    gemm_pers<128, 64, 1, 5, 8><<<GRID, 256, 0, stream>>>(
        wb + wOff[2], y1, affine + afOff[1], nullptr, mx, mn, stats + stOff[2],
        stats + stOff[2] + 128 * 128, 2048);
    finalize_kernel<<<1, 256, 0, stream>>>(stats + stOff[2], stats + stOff[2] + 128 * 128,
                                           G[2], Bi[2], affine + afOff[2], 128, ic0);
    final_out_kernel<<<(128 * 8192) / 256, 256, 0, stream>>>(mx, mn, affine + afOff[2], out1,
                                                             128, 0);

    // ---- branch 1 ----
    gemm_gather<64, 96, 6, 16><<<2048, 256, 0, stream>>>(
        wb + wOff[3], idx1, ftp, out0, y0, stats + stOff[3], stats + stOff[3] + 64 * 128);
    finalize_kernel<<<1, 256, 0, stream>>>(stats + stOff[3], stats + stOff[3] + 64 * 128,
                                           G[3], Bi[3], affine + afOff[3], 64, ic1);
    gemm_pers<128, 64, 0, 6, 8><<<GRID, 256, 0, stream>>>(
        wb + wOff[4], y0, affine + afOff[3], y1, nullptr, nullptr, stats + stOff[4],
        stats + stOff[4] + 128 * 128, 4096);
    finalize_kernel<<<1, 256, 0, stream>>>(stats + stOff[4], stats + stOff[4] + 128 * 128,
                                           G[4], Bi[4], affine + afOff[4], 128, ic1);
    gemm_pers<256, 128, 1, 6, 4><<<GRID, 256, 0, stream>>>(
        wb + wOff[5], y1, affine + afOff[4], nullptr, mx, mn, stats + stOff[5],
        stats + stOff[5] + 256 * 128, 8192);
    finalize_kernel<<<1, 256, 0, stream>>>(stats + stOff[5], stats + stOff[5] + 256 * 128,
                                           G[5], Bi[5], affine + afOff[5], 256, ic1);
    final_out_kernel<<<(256 * 8192) / 256, 256, 0, stream>>>(mx, mn, affine + afOff[5], out1,
                                                             256, 128);
}

// Round 15
// 1515.796 us; speedup vs baseline: 1.1542x; 1.0049x over previous
//
#include <hip/hip_runtime.h>
#include <hip/hip_bf16.h>
#include <cstdint>

// B=8, N=8192, S=1024, C=64
// branch0: r=0.4, K=32, layers 64x67, 64x64, 128x64
// branch1: r=0.8, K=64, layers 64x67, 128x64, 256x128

typedef __attribute__((ext_vector_type(8))) short short8;
typedef __attribute__((ext_vector_type(4))) float f32x4;
typedef __attribute__((ext_vector_type(2))) float f32x2;

__device__ __forceinline__ float bf2f(unsigned short u) {
    return __uint_as_float(((unsigned)u) << 16);
}
__device__ __forceinline__ unsigned short f2bf(float f) {
    unsigned u = __float_as_uint(f);
    return (unsigned short)((u + 0x7fffu + ((u >> 16) & 1u)) >> 16);  // RNE
}

// Wave-64 reductions on the VALU pipe via DPP (rocPRIM pattern): result in lane 63.
__device__ __forceinline__ float wave_red_max_f32(float v) {
#define DPPSTEP(ctrl)                                                                  \
    {                                                                                  \
        int _t = __builtin_amdgcn_update_dpp((int)0xFF800000, __float_as_int(v), ctrl, \
                                             0xf, 0xf, false);                         \
        v = fmaxf(v, __int_as_float(_t));                                              \
    }
    DPPSTEP(0x111) DPPSTEP(0x112) DPPSTEP(0x114) DPPSTEP(0x118) DPPSTEP(0x142) DPPSTEP(0x143)
#undef DPPSTEP
    return v;
}
__device__ __forceinline__ unsigned wave_red_min_u32(unsigned v) {
#define DPPSTEP(ctrl)                                                                   \
    {                                                                                   \
        unsigned _t = (unsigned)__builtin_amdgcn_update_dpp((int)0xFFFFFFFF, (int)v,    \
                                                            ctrl, 0xf, 0xf, false);     \
        v = v < _t ? v : _t;                                                            \
    }
    DPPSTEP(0x111) DPPSTEP(0x112) DPPSTEP(0x114) DPPSTEP(0x118) DPPSTEP(0x142) DPPSTEP(0x143)
#undef DPPSTEP
    return v;
}
__device__ __forceinline__ unsigned long long u64max(unsigned long long a, unsigned long long b) {
    return a > b ? a : b;
}
__device__ __forceinline__ unsigned u32min(unsigned a, unsigned b) { return a < b ? a : b; }

// ---------------- workspace layout (bytes); peak = 224,395,264 ------------------
static const size_t OFF_WBF   = 0;          // packed bf16 weights, 65536 elems (128 KB)
static const size_t OFF_STATS = 262144;     // 704 ch * 128 slots * 2 * 4B
static const size_t STATS_BYTES = 720896;
static const size_t OFF_AFF   = 1048576;    // per-layer scale/shift (final_out layers only)
static const size_t OFF_IDX0  = 2097152;    // 8*1024*32 ints
static const size_t OFF_IDX1  = 3145728;    // 8*1024*64 ints
static const size_t OFF_MX    = 5242880;    // 256*8192 fp32
static const size_t OFF_MN    = 13631488;
static const size_t OFF_Y0    = 22020096;   // bf16 X^T [NCOL][64]  (max 67 MB)
static const size_t OFF_Y1    = 90177536;   // bf16 X^T [NCOL][128] (max 134 MB)
static const size_t OFF_FEATT = 211812352;  // bf16 [8*8192][96] = 12.58 MB, overlaps Y1 tail
// (featTp last read in br1-L0; Y1 beyond 121.6 MB only written by br1-L1, which runs later)

// ---------------- fused pre-kernel (256 threads/block):
// FPS (blocks 0..7) + feat transpose (8..1031) + weight pack (1032..1287) ----
__global__ __launch_bounds__(256) void fused_pre(
    const float* __restrict__ xyz, const float* __restrict__ feat,
    float* __restrict__ newxyz, unsigned short* __restrict__ ft,
    const float* __restrict__ w0, const float* __restrict__ w1, const float* __restrict__ w2,
    const float* __restrict__ w3, const float* __restrict__ w4, const float* __restrict__ w5,
    unsigned short* __restrict__ wb) {
    __shared__ union alignas(16) SM {
        struct {
            float ptsx[8200], ptsy[8200], ptsz[8200];
            float ldsM[16][3];
            float meanv[3];
            alignas(16) unsigned long long sKey[2][4];
            float cbuf[3072];
        } f;
        float tile[64][65];
    } sm;
    const int tid = threadIdx.x;

    if (blockIdx.x >= 1032) {
        int id = (int)(blockIdx.x - 1032) * 256 + tid;  // 0..65535
        const int psz[6] = {6144, 4096, 8192, 6144, 8192, 32768};
        const int Kp[6] = {96, 64, 64, 96, 64, 128};
        const int Ks[6] = {67, 64, 64, 67, 64, 128};
        const float* wp[6] = {w0, w1, w2, w3, w4, w5};
        int off = 0;
        for (int l = 0; l < 6; ++l) {
            if (id < off + psz[l]) {
                int e = id - off;
                int m = e / Kp[l], k = e - m * Kp[l];
                float v = (k < Ks[l]) ? wp[l][m * Ks[l] + k] : 0.f;
                wb[id] = f2bf(v);
                return;
            }
            off += psz[l];
        }
        return;
    }

    if (blockIdx.x >= 8) {
        int tb = (int)blockIdx.x - 8;  // 0..1023
        int b = tb >> 7;
        int j0 = (tb & 127) * 64;
#pragma unroll
        for (int i = 0; i < 16; ++i) {
            int e = i * 256 + tid;
            int c = e >> 6, j = e & 63;
            sm.tile[j][c] = feat[((size_t)b * 64 + c) * 8192 + j0 + j];
        }
        __syncthreads();
#pragma unroll
        for (int i = 0; i < 16; ++i) {
            int e = i * 256 + tid;
            int j = e >> 6, c = e & 63;
            ft[((size_t)(b * 8192 + j0 + j)) * 96 + 3 + c] = f2bf(sm.tile[j][c]);
        }
        if (tid < 64) {
            int j = tid;
            size_t base = ((size_t)(b * 8192 + j0 + j)) * 96;
            const float* xp = xyz + ((size_t)b * 8192 + j0 + j) * 3;
            ft[base + 0] = f2bf(xp[0]);
            ft[base + 1] = f2bf(xp[1]);
            ft[base + 2] = f2bf(xp[2]);
        } else if (tid < 128) {
            int j = tid - 64;
            size_t base = ((size_t)(b * 8192 + j0 + j)) * 96;
            for (int c = 67; c < 96; ++c) ft[base + c] = 0;
        }
        return;
    }

    // ---- FPS: 4 waves (1/SIMD), 32 pts/thread, in-loop running argmax (R13) ----
    const int b = blockIdx.x;
    const int t = tid;
    const int lane = t & 63, wv = t >> 6;
    const float* xb = xyz + (size_t)b * 8192 * 3;

    f32x2 px[16], py[16], pz[16], d[16];
#pragma unroll
    for (int k = 0; k < 16; ++k) {
        int q0 = t + 256 * (2 * k);
        int q1 = t + 256 * (2 * k + 1);
        px[k].x = xb[q0 * 3 + 0]; px[k].y = xb[q1 * 3 + 0];
        py[k].x = xb[q0 * 3 + 1]; py[k].y = xb[q1 * 3 + 1];
        pz[k].x = xb[q0 * 3 + 2]; pz[k].y = xb[q1 * 3 + 2];
        d[k].x = 1e10f; d[k].y = 1e10f;
        sm.f.ptsx[q0 + 1] = px[k].x; sm.f.ptsx[q1 + 1] = px[k].y;
        sm.f.ptsy[q0 + 1] = py[k].x; sm.f.ptsy[q1 + 1] = py[k].y;
        sm.f.ptsz[q0 + 1] = pz[k].x; sm.f.ptsz[q1 + 1] = pz[k].y;
    }
    {
        float sx[4], sy[4], sz[4];
#pragma unroll
        for (int m = 0; m < 4; ++m) {
            int u = (t + 256 * m + 1023) & 1023;
            float ax = 0.f, ay = 0.f, az = 0.f;
#pragma unroll
            for (int jj = 0; jj < 8; ++jj) {
                int ia = u + 1024 * jj;
                ax += xb[ia * 3 + 0]; ay += xb[ia * 3 + 1]; az += xb[ia * 3 + 2];
            }
            sx[m] = ax; sy[m] = ay; sz[m] = az;
        }
#pragma unroll
        for (int off = 32; off; off >>= 1) {
#pragma unroll
            for (int m = 0; m < 4; ++m) {
                sx[m] += __shfl_xor(sx[m], off, 64);
                sy[m] += __shfl_xor(sy[m], off, 64);
                sz[m] += __shfl_xor(sz[m], off, 64);
            }
        }
        if (lane == 0) {
#pragma unroll
            for (int m = 0; m < 4; ++m) {
                sm.f.ldsM[wv + 4 * m][0] = sx[m];
                sm.f.ldsM[wv + 4 * m][1] = sy[m];
                sm.f.ldsM[wv + 4 * m][2] = sz[m];
            }
        }
    }
    __syncthreads();
    if (t < 3) {
        float s = 0.f;
        for (int w = 0; w < 16; ++w) s += sm.f.ldsM[w][t];
        sm.f.meanv[t] = s * (1.f / 8192.f);
    }
    __syncthreads();
    float cx = sm.f.meanv[0], cy = sm.f.meanv[1], cz = sm.f.meanv[2];
    const float mmx = cx, mmy = cy, mmz = cz;
    float dm = 1e10f;
    if (t == 0) { sm.f.ptsx[0] = cx; sm.f.ptsy[0] = cy; sm.f.ptsz[0] = cz; }
    __syncthreads();

    for (int it = 0; it < 1024; ++it) {
        if (t == 0) {
            sm.f.cbuf[it * 3 + 0] = cx;
            sm.f.cbuf[it * 3 + 1] = cy;
            sm.f.cbuf[it * 3 + 2] = cz;
        }
        f32x2 c0, c1, c2;
        c0.x = cx; c0.y = cx; c1.x = cy; c1.y = cy; c2.x = cz; c2.y = cz;
        float bv = -1e30f;
        unsigned bi = 0u;
        {
#pragma clang fp contract(off)
#pragma unroll
            for (int k = 0; k < 16; ++k) {
                f32x2 dx = px[k] - c0;
                f32x2 dy = py[k] - c1;
                f32x2 dz = pz[k] - c2;
                f32x2 dd = (dx * dx + dy * dy) + dz * dz;
                f32x2 nd = __builtin_elementwise_min(d[k], dd);
                d[k] = nd;
                bool g0 = nd.x > bv;
                bv = fmaxf(bv, nd.x);
                bi = g0 ? (unsigned)(t + 256 * (2 * k) + 1) : bi;
                bool g1 = nd.y > bv;
                bv = fmaxf(bv, nd.y);
                bi = g1 ? (unsigned)(t + 256 * (2 * k + 1) + 1) : bi;
            }
        }
        if (t == 0) {
            float dx = __fsub_rn(mmx, cx);
            float dy = __fsub_rn(mmy, cy);
            float dz = __fsub_rn(mmz, cz);
            float dd = __fadd_rn(__fadd_rn(__fmul_rn(dx, dx), __fmul_rn(dy, dy)), __fmul_rn(dz, dz));
            dm = fminf(dm, dd);
            bv = fmaxf(bv, dm);
        }
        float wm = wave_red_max_f32(bv);
        float bmaxw = __int_as_float(__builtin_amdgcn_readlane(__float_as_int(wm), 63));
        unsigned mi = (bv == bmaxw) ? bi : 0xFFFFFFFFu;
        if (t == 0 && dm == bmaxw) mi = 0u;
        unsigned wmin = wave_red_min_u32(mi);
        unsigned miw = (unsigned)__builtin_amdgcn_readlane((int)wmin, 63);
        int par = it & 1;
        if (lane == 0)
            sm.f.sKey[par][wv] = ((unsigned long long)__float_as_uint(bmaxw) << 32) |
                                 (unsigned long long)(8192u - miw);
        __syncthreads();
        ulonglong2 kp0 = *(const ulonglong2*)&sm.f.sKey[par][0];
        ulonglong2 kp1 = *(const ulonglong2*)&sm.f.sKey[par][2];
        unsigned long long kk = u64max(u64max(kp0.x, kp0.y), u64max(kp1.x, kp1.y));
        int far = 8192 - (int)(unsigned)(kk & 0xffffffffull);
        cx = sm.f.ptsx[far];
        cy = sm.f.ptsy[far];
        cz = sm.f.ptsz[far];
    }
    __syncthreads();
    float* ob = newxyz + (size_t)b * 3072;
#pragma unroll
    for (int i = 0; i < 12; ++i) ob[t + 256 * i] = sm.f.cbuf[t + 256 * i];
}

// ---------------- merged ball query: blocks 0..2047 br0 (K=32), 2048..4095 br1 --
__global__ void ball_query2(const float* __restrict__ xyz, const float* __restrict__ newxyz,
                            int* __restrict__ idx0, int* __restrict__ idx1) {
    int bid = blockIdx.x;
    int br = (bid >= 2048);
    int K = br ? 64 : 32;
    float r2 = br ? (0.8f * 0.8f) : (0.4f * 0.4f);
    int* idxout = br ? idx1 : idx0;
    int wid = (((bid & 2047) * 256) + threadIdx.x) >> 6;
    int lane = threadIdx.x & 63;
    int b = wid >> 10;
    const float* q = newxyz + (size_t)wid * 3;
    float qx = q[0], qy = q[1], qz = q[2];
    const float* xb = xyz + (size_t)b * 8192 * 3;
    int* out = idxout + (size_t)wid * K;
    int count = 0;
    int first = 0;
    for (int base = 0; base < 8192 && count < K; base += 64) {
        int j = base + lane;
        float dx = __fsub_rn(xb[j * 3 + 0], qx);
        float dy = __fsub_rn(xb[j * 3 + 1], qy);
        float dz = __fsub_rn(xb[j * 3 + 2], qz);
        float d2 = __fadd_rn(__fadd_rn(__fmul_rn(dx, dx), __fmul_rn(dy, dy)), __fmul_rn(dz, dz));
        bool in = d2 < r2;
        unsigned long long m = __ballot(in);
        if (count == 0 && m) first = base + __ffsll((long long)m) - 1;
        if (in) {
            int pos = count + __popcll(m & ((1ull << lane) - 1ull));
            if (pos < K) out[pos] = j;
        }
        count += __popcll(m);
    }
    if (count < K) {
        int fillv = (count > 0) ? first : 0;
        for (int p = count + lane; p < K; p += 64) out[p] = fillv;
    }
}

// ---------------- persistent double-buffered gather GEMM (L0 layers) ------------
// Two-level pipeline: aux(t+2G) staged into alternate aux LDS buffer and
// gather(t+G) staged into alternate Bs buffer while MFMA(t) runs. One barrier
// per tile. Stats accumulate in registers; one atomic set per block.
template <int Mp, int Kp, int KSH, int NT>
__global__ __launch_bounds__(256) void gemm_gather_pers(
    const unsigned short* __restrict__ Wb, const int* __restrict__ idx,
    const unsigned short* __restrict__ ftp, const float* __restrict__ newxyz,
    unsigned short* __restrict__ Yout, float* __restrict__ statS, float* __restrict__ statQ,
    int ntiles) {
    constexpr int MT = Mp / 64;
    constexpr int KS = Kp / 32;
    constexpr int NC = NT * 16;
    constexpr int NCHUNK = NT * KS * 64;
    constexpr int CPT = NCHUNK / 256;
    __shared__ unsigned short Bs[2][NCHUNK * 8];
    __shared__ float sAuxF[2][NC * 4];  // [idx(int) | qx | qy | qz] per col

    const int tid = threadIdx.x;
    const int w = tid >> 6;
    const int lane = tid & 63;
    const int n = lane & 15;
    const int quad = lane >> 4;
    const int rbase = w * (Mp / 4);
    const int G = (int)gridDim.x;

    int colC[CPT], kcC[CPT];
    {
        int pl = tid & 63;
        int pn = pl & 15;
        int pq = pl >> 4;
#pragma unroll
        for (int i = 0; i < CPT; ++i) {
            int rest = i * 4 + (tid >> 6);
            int pks = rest % KS;
            int pnt = rest / KS;
            colC[i] = pnt * 16 + pn;
            kcC[i] = pks * 4 + pq;
        }
    }

    short8 a[MT][KS];
#pragma unroll
    for (int mt = 0; mt < MT; ++mt)
#pragma unroll
        for (int ks = 0; ks < KS; ++ks)
            a[mt][ks] = *(const short8*)(Wb + (size_t)(rbase + mt * 16 + n) * Kp + ks * 32 + quad * 8);

    float accS[MT][4], accQ[MT][4];
#pragma unroll
    for (int mt = 0; mt < MT; ++mt)
#pragma unroll
        for (int r = 0; r < 4; ++r) { accS[mt][r] = 0.f; accQ[mt][r] = 0.f; }

#define STAGE_AUX(TILE, AUXI)                                   \
    {                                                           \
        long scol0 = (long)(TILE) * NC;                         \
        if (tid < NC) {                                         \
            long colg = scol0 + tid;                            \
            ((int*)&sAuxF[(AUXI)][0])[tid] = idx[colg];         \
            long sk = colg >> KSH;                              \
            sAuxF[(AUXI)][NC + tid] = newxyz[sk * 3 + 0];       \
            sAuxF[(AUXI)][2 * NC + tid] = newxyz[sk * 3 + 1];   \
            sAuxF[(AUXI)][3 * NC + tid] = newxyz[sk * 3 + 2];   \
        }                                                       \
    }

#define STAGE_GATHER(TILE, BUFI, AUXI)                                                   \
    {                                                                                    \
        long scol0 = (long)(TILE) * NC;                                                  \
        const int bb = (int)(scol0 >> (KSH + 10));                                       \
        int jj[CPT];                                                                     \
        _Pragma("unroll") for (int i = 0; i < CPT; ++i)                                  \
            jj[i] = ((const int*)&sAuxF[(AUXI)][0])[colC[i]];                            \
        short8 raw[CPT];                                                                 \
        _Pragma("unroll") for (int i = 0; i < CPT; ++i)                                  \
            raw[i] = *(const short8*)(ftp + ((long)(bb * 8192 + jj[i])) * 96 + kcC[i] * 8); \
        _Pragma("unroll") for (int i = 0; i < CPT; ++i) {                                \
            short8 v = raw[i];                                                           \
            if (kcC[i] == 0) {                                                           \
                v[0] = (short)f2bf(bf2f((unsigned short)v[0]) - sAuxF[(AUXI)][NC + colC[i]]); \
                v[1] = (short)f2bf(bf2f((unsigned short)v[1]) - sAuxF[(AUXI)][2 * NC + colC[i]]); \
                v[2] = (short)f2bf(bf2f((unsigned short)v[2]) - sAuxF[(AUXI)][3 * NC + colC[i]]); \
            }                                                                            \
            *(short8*)(&Bs[(BUFI)][(i * 256 + tid) * 8]) = v;                            \
        }                                                                                \
    }

    // prologue: aux(t0) -> sAux[0]; gather(t0) -> Bs[0]; aux(t0+G) -> sAux[1]
    const int t0 = (int)blockIdx.x;
    STAGE_AUX(t0, 0)
    __syncthreads();
    STAGE_GATHER(t0, 0, 0)
    if (t0 + G < ntiles) STAGE_AUX(t0 + G, 1)
    __syncthreads();

    int g = 0;
    for (int t = t0; t < ntiles; t += G, ++g) {
        const int cur = g & 1;
        const int nxt = cur ^ 1;
        // prefetch: gather(t+G) from sAux[nxt]; aux(t+2G) into sAux[cur]
        if (t + G < ntiles) STAGE_GATHER(t + G, nxt, nxt)
        if (t + 2 * G < ntiles) STAGE_AUX(t + 2 * G, cur)

        const long col0 = (long)t * NC;
        f32x4 acc[MT][NT];
#pragma unroll
        for (int mt = 0; mt < MT; ++mt)
#pragma unroll
            for (int nt = 0; nt < NT; ++nt)
#pragma unroll
                for (int r = 0; r < 4; ++r) acc[mt][nt][r] = 0.f;

#pragma unroll
        for (int ks = 0; ks < KS; ++ks) {
#pragma unroll
            for (int nt = 0; nt < NT; ++nt) {
                short8 bfr = *(const short8*)(&Bs[cur][((nt * KS + ks) * 64 + lane) * 8]);
#pragma unroll
                for (int mt = 0; mt < MT; ++mt)
                    acc[mt][nt] =
                        __builtin_amdgcn_mfma_f32_16x16x32_bf16(a[mt][ks], bfr, acc[mt][nt], 0, 0, 0);
            }
        }

#pragma unroll
        for (int mt = 0; mt < MT; ++mt)
#pragma unroll
            for (int r = 0; r < 4; ++r) {
                float s = accS[mt][r], q = accQ[mt][r];
#pragma unroll
                for (int nt = 0; nt < NT; ++nt) {
                    float v = acc[mt][nt][r];
                    s += v;
                    q = fmaf(v, v, q);
                }
                accS[mt][r] = s;
                accQ[mt][r] = q;
            }

#pragma unroll
        for (int mt = 0; mt < MT; ++mt)
#pragma unroll
            for (int nt = 0; nt < NT; ++nt) {
                long col = col0 + nt * 16 + n;
                unsigned p0 = f2bf(acc[mt][nt][0]) | ((unsigned)f2bf(acc[mt][nt][1]) << 16);
                unsigned p1 = f2bf(acc[mt][nt][2]) | ((unsigned)f2bf(acc[mt][nt][3]) << 16);
                uint2 st; st.x = p0; st.y = p1;
                *(uint2*)(Yout + col * Mp + rbase + mt * 16 + quad * 4) = st;
            }
        __syncthreads();
    }

    const int slot = (int)(blockIdx.x & 127);
#pragma unroll
    for (int mt = 0; mt < MT; ++mt)
#pragma unroll
        for (int r = 0; r < 4; ++r) {
            float s = accS[mt][r], q = accQ[mt][r];
#pragma unroll
            for (int off = 1; off < 16; off <<= 1) {
                s += __shfl_xor(s, off, 16);
                q += __shfl_xor(q, off, 16);
            }
            if (n == 0) {
                int ch = rbase + mt * 16 + quad * 4 + r;
                atomicAdd(statS + (size_t)ch * 128 + slot, s);
                atomicAdd(statQ + (size_t)ch * 128 + slot, q);
            }
        }
#undef STAGE_AUX
#undef STAGE_GATHER
}

// ---------------- persistent double-buffered MFMA GEMM (IN_MODE 1 layers) -------
// Inline BN-finalize: each block computes the previous layer's affine from its
// stats at block start (same ascending-k summation order as finalize_kernel ->
// identical values), removing the separate finalize launch.
#define STAGE_IN1(TILE, BUFI)                                                       \
    {                                                                               \
        long scol0 = (long)(TILE) * NC;                                             \
        short8 raw[CPT];                                                            \
        _Pragma("unroll") for (int i = 0; i < CPT; ++i)                             \
            raw[i] = *(const short8*)(Xin + (scol0 + colC[i]) * (long)Kp + kcC[i] * 8); \
        _Pragma("unroll") for (int i = 0; i < CPT; ++i) {                           \
            short8 v;                                                               \
            _Pragma("unroll") for (int e = 0; e < 8; ++e) {                         \
                float xf = bf2f((unsigned short)raw[i][e]);                         \
                xf = fmaxf(fmaf(xf, sAff[kcC[i] * 8 + e], sAff[Kp + kcC[i] * 8 + e]), 0.f); \
                v[e] = (short)f2bf(xf);                                             \
            }                                                                       \
            *(short8*)(&Bs[(BUFI)][(i * 256 + tid) * 8]) = v;                       \
        }                                                                           \
    }

template <int Mp, int Kp, int OUT_MODE, int KSH, int NT>
__global__ __launch_bounds__(256) void gemm_pers(
    const unsigned short* __restrict__ Wb, const unsigned short* __restrict__ Xin,
    const float* __restrict__ pS, const float* __restrict__ pQ,
    const float* __restrict__ gW, const float* __restrict__ bW, float invC,
    unsigned short* __restrict__ Yout, float* __restrict__ MX, float* __restrict__ MN,
    float* __restrict__ statS, float* __restrict__ statQ, int ntiles) {
    constexpr int MT = Mp / 64;
    constexpr int KS = Kp / 32;
    constexpr int NC = NT * 16;
    constexpr int NCHUNK = NT * KS * 64;
    constexpr int CPT = NCHUNK / 256;
    __shared__ unsigned short Bs[2][NCHUNK * 8];
    __shared__ float sAff[2 * 128];

    const int tid = threadIdx.x;
    const int w = tid >> 6;
    const int lane = tid & 63;
    const int n = lane & 15;
    const int quad = lane >> 4;
    const int rbase = w * (Mp / 4);

    int colC[CPT], kcC[CPT];
    {
        int pl = tid & 63;
        int pn = pl & 15;
        int pq = pl >> 4;
#pragma unroll
        for (int i = 0; i < CPT; ++i) {
            int rest = i * 4 + (tid >> 6);
            int pks = rest % KS;
            int pnt = rest / KS;
            colC[i] = pnt * 16 + pn;
            kcC[i] = pks * 4 + pq;
        }
    }

    short8 a[MT][KS];
#pragma unroll
    for (int mt = 0; mt < MT; ++mt)
#pragma unroll
        for (int ks = 0; ks < KS; ++ks)
            a[mt][ks] = *(const short8*)(Wb + (size_t)(rbase + mt * 16 + n) * Kp + ks * 32 + quad * 8);

    // inline finalize of previous layer's BN (Kp input channels)
    if (tid < Kp) {
        const f32x4* s4 = (const f32x4*)(pS + (size_t)tid * 128);
        const f32x4* q4 = (const f32x4*)(pQ + (size_t)tid * 128);
        float s = 0.f, q = 0.f;
#pragma unroll 4
        for (int k = 0; k < 32; ++k) {
            f32x4 vs = s4[k];
            f32x4 vq = q4[k];
            s += vs.x; s += vs.y; s += vs.z; s += vs.w;  // ascending-k order kept
            q += vq.x; q += vq.y; q += vq.z; q += vq.w;
        }
        float mean = s * invC;
        float var = fmaxf(q * invC - mean * mean, 0.f);
        float sc = gW[tid] / sqrtf(var + 1e-5f);
        float sh = bW[tid] - mean * sc;
        sAff[tid] = sc;
        sAff[Kp + tid] = sh;
    }
    float accS[MT][4], accQ[MT][4];
#pragma unroll
    for (int mt = 0; mt < MT; ++mt)
#pragma unroll
        for (int r = 0; r < 4; ++r) { accS[mt][r] = 0.f; accQ[mt][r] = 0.f; }
    __syncthreads();  // sAff ready

    if ((int)blockIdx.x < ntiles) STAGE_IN1((int)blockIdx.x, 0);
    __syncthreads();

    int g = 0;
    for (int t = (int)blockIdx.x; t < ntiles; t += (int)gridDim.x, ++g) {
        int tn = t + (int)gridDim.x;
        if (tn < ntiles) STAGE_IN1(tn, (g + 1) & 1);

        const int cur = g & 1;
        const long col0 = (long)t * NC;
        f32x4 acc[MT][NT];
#pragma unroll
        for (int mt = 0; mt < MT; ++mt)
#pragma unroll
            for (int nt = 0; nt < NT; ++nt)
#pragma unroll
                for (int r = 0; r < 4; ++r) acc[mt][nt][r] = 0.f;

#pragma unroll
        for (int ks = 0; ks < KS; ++ks) {
#pragma unroll
            for (int nt = 0; nt < NT; ++nt) {
                short8 bfr = *(const short8*)(&Bs[cur][((nt * KS + ks) * 64 + lane) * 8]);
#pragma unroll
                for (int mt = 0; mt < MT; ++mt)
                    acc[mt][nt] =
                        __builtin_amdgcn_mfma_f32_16x16x32_bf16(a[mt][ks], bfr, acc[mt][nt], 0, 0, 0);
            }
        }

#pragma unroll
        for (int mt = 0; mt < MT; ++mt)
#pragma unroll
            for (int r = 0; r < 4; ++r) {
                float s = accS[mt][r], q = accQ[mt][r];
#pragma unroll
                for (int nt = 0; nt < NT; ++nt) {
                    float v = acc[mt][nt][r];
                    s += v;
                    q = fmaf(v, v, q);
                }
                accS[mt][r] = s;
                accQ[mt][r] = q;
            }

        if constexpr (OUT_MODE == 0) {
#pragma unroll
            for (int mt = 0; mt < MT; ++mt)
#pragma unroll
                for (int nt = 0; nt < NT; ++nt) {
                    long col = col0 + nt * 16 + n;
                    unsigned p0 = f2bf(acc[mt][nt][0]) | ((unsigned)f2bf(acc[mt][nt][1]) << 16);
                    unsigned p1 = f2bf(acc[mt][nt][2]) | ((unsigned)f2bf(acc[mt][nt][3]) << 16);
                    uint2 st; st.x = p0; st.y = p1;
                    *(uint2*)(Yout + col * Mp + rbase + mt * 16 + quad * 4) = st;
                }
        } else {
            constexpr int GRP = (1 << KSH) / 16;
            constexpr int NG = NT / GRP;
#pragma unroll
            for (int mt = 0; mt < MT; ++mt)
#pragma unroll
                for (int r = 0; r < 4; ++r) {
#pragma unroll
                    for (int gh = 0; gh < NG; ++gh) {
                        float mx = acc[mt][GRP * gh][r], mn = acc[mt][GRP * gh][r];
#pragma unroll
                        for (int e = 1; e < GRP; ++e) {
                            mx = fmaxf(mx, acc[mt][GRP * gh + e][r]);
                            mn = fminf(mn, acc[mt][GRP * gh + e][r]);
                        }
#pragma unroll
                        for (int off = 1; off < 16; off <<= 1) {
                            mx = fmaxf(mx, __shfl_xor(mx, off, 16));
                            mn = fminf(mn, __shfl_xor(mn, off, 16));
                        }
                        if (n == 0) {
                            int ch = rbase + mt * 16 + quad * 4 + r;
                            long gg = (col0 >> KSH) + gh;
                            MX[(long)ch * 8192 + gg] = mx;
                            MN[(long)ch * 8192 + gg] = mn;
                        }
                    }
                }
        }
        __syncthreads();
    }

    const int slot = (int)(blockIdx.x & 127);
#pragma unroll
    for (int mt = 0; mt < MT; ++mt)
#pragma unroll
        for (int r = 0; r < 4; ++r) {
            float s = accS[mt][r], q = accQ[mt][r];
#pragma unroll
            for (int off = 1; off < 16; off <<= 1) {
                s += __shfl_xor(s, off, 16);
                q += __shfl_xor(q, off, 16);
            }
            if (n == 0) {
                int ch = rbase + mt * 16 + quad * 4 + r;
                atomicAdd(statS + (size_t)ch * 128 + slot, s);
                atomicAdd(statQ + (size_t)ch * 128 + slot, q);
            }
        }
}

// ---------------- finalize BN constants (for final_out layers only) --------------
__global__ void finalize_kernel(const float* __restrict__ sS, const float* __restrict__ sQ,
                                const float* __restrict__ g, const float* __restrict__ b,
                                float* __restrict__ aff, int C, float invCount) {
    int c = threadIdx.x + blockIdx.x * blockDim.x;
    if (c >= C) return;
    float s = 0.f, q = 0.f;
    for (int k = 0; k < 128; ++k) { s += sS[c * 128 + k]; q += sQ[c * 128 + k]; }
    float mean = s * invCount;
    float var = fmaxf(q * invCount - mean * mean, 0.f);
    float sc = g[c] / sqrtf(var + 1e-5f);
    float sh = b[c] - mean * sc;
    aff[c] = sc;
    aff[C + c] = sh;
}

// ---------------- final output ---------------------------------------------------
__global__ void final_out_kernel(const float* __restrict__ MX, const float* __restrict__ MN,
                                 const float* __restrict__ aff, float* __restrict__ out1,
                                 int Cout, int cOff) {
    long i = (long)blockIdx.x * 256 + threadIdx.x;
    int c = (int)(i >> 13);
    int gidx = (int)(i & 8191);
    int b = gidx >> 10, s = gidx & 1023;
    float sc = aff[c], sh = aff[Cout + c];
    float v = fmaxf(fmaxf(sc * MX[i] + sh, sc * MN[i] + sh), 0.f);
    out1[((long)b * 384 + cOff + c) * 1024 + s] = v;
}

// ---------------- host -----------------------------------------------------------
extern "C" void kernel_launch(void* const* d_in, const int* in_sizes, int n_in,
                              void* d_out, int out_size, void* d_ws, size_t ws_size,
                              hipStream_t stream) {
    const float* xyz = (const float*)d_in[0];
    const float* feat = (const float*)d_in[1];
    const float *W[6], *G[6], *Bi[6];
    for (int l = 0; l < 6; ++l) {
        W[l] = (const float*)d_in[2 + l * 3];
        G[l] = (const float*)d_in[3 + l * 3];
        Bi[l] = (const float*)d_in[4 + l * 3];
    }
    char* ws = (char*)d_ws;
    float* out0 = (float*)d_out;
    float* out1 = (float*)d_out + 24576;

    unsigned short* wb = (unsigned short*)(ws + OFF_WBF);
    float* stats = (float*)(ws + OFF_STATS);
    float* affine = (float*)(ws + OFF_AFF);
    int* idx0 = (int*)(ws + OFF_IDX0);
    int* idx1 = (int*)(ws + OFF_IDX1);
    float* mx = (float*)(ws + OFF_MX);
    float* mn = (float*)(ws + OFF_MN);
    unsigned short* y0 = (unsigned short*)(ws + OFF_Y0);
    unsigned short* y1 = (unsigned short*)(ws + OFF_Y1);
    unsigned short* ftp = (unsigned short*)(ws + OFF_FEATT);

    hipMemsetAsync(stats, 0, STATS_BYTES, stream);
    fused_pre<<<1288, 256, 0, stream>>>(xyz, feat, out0, ftp, W[0], W[1], W[2], W[3], W[4],
                                        W[5], wb);
    ball_query2<<<4096, 256, 0, stream>>>(xyz, out0, idx0, idx1);

    const int wOff[6] = {0, 6144, 10240, 18432, 24576, 32768};
    int stOff[6], afOff[6];
    {
        const int Cs[6] = {64, 64, 128, 64, 128, 256};
        int so = 0, ao = 0;
        for (int l = 0; l < 6; ++l) {
            stOff[l] = so; so += Cs[l] * 256;
            afOff[l] = ao; ao += Cs[l] * 2;
        }
    }
    const float ic0 = 1.f / (float)(8L * 1024 * 32);
    const float ic1 = 1.f / (float)(8L * 1024 * 64);
    const int GRID = 768;

    // ---- branch 0 ----
    gemm_gather_pers<64, 96, 5, 8><<<GRID, 256, 0, stream>>>(
        wb + wOff[0], idx0, ftp, out0, y0, stats + stOff[0], stats + stOff[0] + 64 * 128, 2048);
    gemm_pers<64, 64, 0, 5, 8><<<GRID, 256, 0, stream>>>(
        wb + wOff[1], y0, stats + stOff[0], stats + stOff[0] + 64 * 128, G[0], Bi[0], ic0, y1,
        nullptr, nullptr, stats + stOff[1], stats + stOff[1] + 64 * 128, 2048);
    gemm_pers<128, 64, 1, 5, 8><<<GRID, 256, 0, stream>>>(
        wb + wOff[2], y1, stats + stOff[1], stats + stOff[1] + 64 * 128, G[1], Bi[1], ic0,
        nullptr, mx, mn, stats + stOff[2], stats + stOff[2] + 128 * 128, 2048);
    finalize_kernel<<<1, 256, 0, stream>>>(stats + stOff[2], stats + stOff[2] + 128 * 128,
                                           G[2], Bi[2], affine + afOff[2], 128, ic0);
    final_out_kernel<<<(128 * 8192) / 256, 256, 0, stream>>>(mx, mn, affine + afOff[2], out1,
                                                             128, 0);

    // ---- branch 1 ----
    gemm_gather_pers<64, 96, 6, 8><<<GRID, 256, 0, stream>>>(
        wb + wOff[3], idx1, ftp, out0, y0, stats + stOff[3], stats + stOff[3] + 64 * 128, 4096);
    gemm_pers<128, 64, 0, 6, 8><<<GRID, 256, 0, stream>>>(
        wb + wOff[4], y0, stats + stOff[3], stats + stOff[3] + 64 * 128, G[3], Bi[3], ic1, y1,
        nullptr, nullptr, stats + stOff[4], stats + stOff[4] + 128 * 128, 4096);
    gemm_pers<256, 128, 1, 6, 4><<<GRID, 256, 0, stream>>>(
        wb + wOff[5], y1, stats + stOff[4], stats + stOff[4] + 128 * 128, G[4], Bi[4], ic1,
        nullptr, mx, mn, stats + stOff[5], stats + stOff[5] + 256 * 128, 8192);
    finalize_kernel<<<1, 256, 0, stream>>>(stats + stOff[5], stats + stOff[5] + 256 * 128,
                                           G[5], Bi[5], affine + afOff[5], 256, ic1);
    final_out_kernel<<<(256 * 8192) / 256, 256, 0, stream>>>(mx, mn, affine + afOff[5], out1,
                                                             256, 128);
}